// Round 7
// baseline (157.260 us; speedup 1.0000x reference)
//
#include <hip/hip_runtime.h>
#include <math.h>

#define B_    4
#define CH_   256
#define H_    48
#define W_    160
#define A_    36
#define K2_   9
#define HW_   (H_*W_)        // 7680
#define NPIX_ (B_*HW_)       // 30720
#define KTOT_ (CH_*K2_)      // 2304
#define CPC_  32             // channels per chunk
#define KC_   (CPC_*K2_)     // 288 k' per chunk
#define NCHK_ (CH_/CPC_)     // 8
#define NKST_ (KTOT_/32)     // 72 k-steps of 32
#define LSTR_ 296            // LDS row stride (ushort) for v11/v2 paths
#define PT2_  64             // pixel tile (col image granularity)
#define NBLK_ (NPIX_/PT2_)   // 480 col pixel-blocks
#define COLB_ 36864          // bytes per (64px-block,chunk) col image: 36 gran*64px*16B
#define COLW_ (COLB_/2)      // 18432 ushorts
#define PT5_  128            // GEMM pixel tile
#define NB5_  (NPIX_/PT5_)   // 240 GEMM blocks
#define TSTR_ 520            // im2col LDS granule stride (ushorts) = 1040B (pad)

typedef __attribute__((ext_vector_type(8))) short bf16x8;
typedef __attribute__((ext_vector_type(4))) float f32x4;

__device__ inline ushort f2bf(float f) {
    union { float f; unsigned u; } c; c.f = f;
    unsigned r = c.u + 0x7FFFu + ((c.u >> 16) & 1u);
    return (ushort)(r >> 16);
}
__device__ inline float bf2f(ushort u) {
    union { unsigned u; float f; } c; c.u = (unsigned)u << 16; return c.f;
}

// async global->LDS, 16B per lane: LDS dest = wave-uniform base + lane*16
__device__ inline void gld_lds16(const ushort* g, ushort* l) {
    __builtin_amdgcn_global_load_lds(
        (const __attribute__((address_space(1))) unsigned int*)(g),
        (__attribute__((address_space(3))) unsigned int*)(l),
        16, 0, 0);
}

// ---------------- weight fp32 -> bf16, MFMA-fragment-ordered ----------------
__global__ __launch_bounds__(256)
void prep_weight2(const float* __restrict__ w, ushort* __restrict__ wp2) {
    int t = blockIdx.x * 256 + threadIdx.x;
    if (t >= CH_ * KTOT_) return;
    int j    = t & 7;
    int lane = (t >> 3) & 63;
    int kk   = t >> 9;             // 0..1151
    int kst  = kk % NKST_;
    int rg   = kk / NKST_;         // 0..15
    int row  = rg * 16 + (lane & 15);
    int kq   = kst * 32 + (lane >> 4) * 8 + j;   // k'
    int chunk = kq / KC_, r = kq % KC_;
    int tap = r / CPC_, ci = r % CPC_;
    int c = chunk * CPC_ + ci;
    wp2[t] = f2bf(w[(row * CH_ + c) * K2_ + tap]);
}

// ---------------- weight fp32 -> bf16, K-permuted (fallback layout) ----------
__global__ __launch_bounds__(256)
void prep_weight(const float* __restrict__ w, ushort* __restrict__ wp) {
    int t = blockIdx.x * 256 + threadIdx.x;
    if (t >= CH_ * KTOT_) return;
    int o  = t / KTOT_, kk = t % KTOT_;
    int chunk = kk / KC_, r = kk % KC_;
    int tap = r / CPC_, ci = r % CPC_;
    int c = chunk * CPC_ + ci;
    wp[t] = f2bf(w[(o * CH_ + c) * K2_ + tap]);
}

// ---------------- x [B,C,HW] f32 -> xt [B,HW,C] bf16 ----------------
__global__ __launch_bounds__(256)
void prep_xt(const float* __restrict__ x, ushort* __restrict__ xt) {
    int bid = blockIdx.x;
    int hwT = bid % (HW_ / 128);           // 60
    int rest = bid / (HW_ / 128);
    int cT = rest & 3;
    int b  = rest >> 2;
    int hw0 = hwT * 128, c0 = cT * 64;
    int tid = threadIdx.x;
    int u = tid & 7, s = tid >> 3;
    const float* xb = x + ((long)b * CH_ + c0 + u * 8) * HW_ + hw0 + s * 4;
    float4 L[8];
    #pragma unroll
    for (int i = 0; i < 8; ++i) L[i] = *(const float4*)(xb + (long)i * HW_);
    ushort* xo = xt + ((long)b * HW_ + hw0 + s * 4) * CH_ + c0 + u * 8;
    #pragma unroll
    for (int j = 0; j < 4; ++j) {
        bf16x8 o;
        #pragma unroll
        for (int i = 0; i < 8; ++i) {
            float f = (j == 0) ? L[i].x : (j == 1) ? L[i].y : (j == 2) ? L[i].z : L[i].w;
            o[i] = (short)f2bf(f);
        }
        *(bf16x8*)(xo + (long)j * CH_) = o;
    }
}

// ======== v18a: gating + FULL bilinear geometry precompute ========
// Per (pix,kt): {int4 corner offsets (xt elem units, no chunk), float4
// weights*m}. 30720 threads do the ~330-op geometry ONCE; im2col (2.2M
// threads) previously re-derived it per chunk (8x redundant) — that setup
// was ~40% of im2col's VALU (57% busy at 54us).
__global__ __launch_bounds__(256)
void gating_geo(const float* __restrict__ prob,
                const float* __restrict__ table,
                int* __restrict__ geo) {
    int pix = blockIdx.x * 256 + threadIdx.x;
    if (pix >= NPIX_) return;
    int b  = pix / HW_;
    int hw = pix % HW_;
    int h  = hw / W_, w_ = hw % W_;
    const float* pr = prob + (long)b * A_ * HW_ + hw;

    float v0 = -1e30f, v1 = -1e30f, v2 = -1e30f;
    int   i0 = 0, i1 = 0, i2 = 0;
    #pragma unroll 4
    for (int a = 0; a < A_; ++a) {
        float v = pr[(long)a * HW_];
        if (v > v0)      { v2=v1; i2=i1; v1=v0; i1=i0; v0=v; i0=a; }
        else if (v > v1) { v2=v1; i2=i1; v1=v;  i1=a; }
        else if (v > v2) { v2=v;  i2=a; }
    }
    float e1 = expf(v1 - v0), e2 = expf(v2 - v0);
    float inv = 1.0f / (1.0f + e1 + e2);
    float s0 = inv, s1 = e1*inv, s2 = e2*inv;
    float hard = (v0 > 0.5f) ? 1.0f : 0.0f;
    float m = v0;

    const float* t0 = table + ((long)i0 * 18) * HW_ + hw;
    const float* t1 = table + ((long)i1 * 18) * HW_ + hw;
    const float* t2 = table + ((long)i2 * 18) * HW_ + hw;

    #pragma unroll
    for (int kt = 0; kt < K2_; ++kt) {
        float offh = (s0 * t0[(long)(2*kt)   * HW_] + s1 * t1[(long)(2*kt)   * HW_]
                    + s2 * t2[(long)(2*kt)   * HW_]) * hard;
        float offw = (s0 * t0[(long)(2*kt+1) * HW_] + s1 * t1[(long)(2*kt+1) * HW_]
                    + s2 * t2[(long)(2*kt+1) * HW_]) * hard;
        float py  = (float)(h  + (kt / 3 - 1)) + offh;
        float pxf = (float)(w_ + (kt % 3 - 1)) + offw;
        float y0f = floorf(py), x0f = floorf(pxf);
        float dy = py - y0f,   dx = pxf - x0f;
        int y0 = (int)y0f, x0i = (int)x0f;
        int y1 = y0 + 1,   x1  = x0i + 1;
        float vy0 = (y0  >= 0 && y0  < H_) ? 1.f : 0.f;
        float vy1 = (y1  >= 0 && y1  < H_) ? 1.f : 0.f;
        float vx0 = (x0i >= 0 && x0i < W_) ? 1.f : 0.f;
        float vx1 = (x1  >= 0 && x1  < W_) ? 1.f : 0.f;
        int cy0 = min(max(y0, 0),  H_-1), cy1 = min(max(y1, 0), H_-1);
        int cx0 = min(max(x0i, 0), W_-1), cx1 = min(max(x1, 0), W_-1);
        int* gp = geo + ((long)pix * K2_ + kt) * 8;
        int4 co; float4 wg;
        co.x = (cy0*W_ + cx0) * CH_;  wg.x = (1.f-dy)*(1.f-dx)*vy0*vx0*m;
        co.y = (cy0*W_ + cx1) * CH_;  wg.y = (1.f-dy)*dx      *vy0*vx1*m;
        co.z = (cy1*W_ + cx0) * CH_;  wg.z = dy      *(1.f-dx)*vy1*vx0*m;
        co.w = (cy1*W_ + cx1) * CH_;  wg.w = dy      *dx      *vy1*vx1*m;
        *(int4*)gp = co;
        *(float4*)(gp + 4) = wg;
    }
}

// ---------------- top-k gating + offset blend (fallback tiers) ----------
__global__ __launch_bounds__(256)
void gating_kernel(const float* __restrict__ prob,
                   const float* __restrict__ table,
                   float* __restrict__ m_out,
                   float* __restrict__ off_out) {
    int pix = blockIdx.x * 256 + threadIdx.x;
    if (pix >= NPIX_) return;
    int b  = pix / HW_;
    int hw = pix % HW_;
    const float* pr = prob + (long)b * A_ * HW_ + hw;

    float v0 = -1e30f, v1 = -1e30f, v2 = -1e30f;
    int   i0 = 0, i1 = 0, i2 = 0;
    #pragma unroll 4
    for (int a = 0; a < A_; ++a) {
        float v = pr[(long)a * HW_];
        if (v > v0)      { v2=v1; i2=i1; v1=v0; i1=i0; v0=v; i0=a; }
        else if (v > v1) { v2=v1; i2=i1; v1=v;  i1=a; }
        else if (v > v2) { v2=v;  i2=a; }
    }
    float e1 = expf(v1 - v0), e2 = expf(v2 - v0);
    float inv = 1.0f / (1.0f + e1 + e2);
    float s0 = inv, s1 = e1*inv, s2 = e2*inv;
    float hard = (v0 > 0.5f) ? 1.0f : 0.0f;

    m_out[pix] = v0;
    const float* t0 = table + ((long)i0 * 18) * HW_ + hw;
    const float* t1 = table + ((long)i1 * 18) * HW_ + hw;
    const float* t2 = table + ((long)i2 * 18) * HW_ + hw;
    float* op = off_out + (long)pix * 18;
    #pragma unroll
    for (int c = 0; c < 18; ++c) {
        float o = s0 * t0[(long)c * HW_] + s1 * t1[(long)c * HW_] + s2 * t2[(long)c * HW_];
        op[c] = o * hard;
    }
}

// ======== v18b: im2col — geo-driven, coalesced gathers AND stores ========
// Same proven k4 pipeline (cluster gather -> blend -> LDS transpose ->
// 1KB-contiguous stores), but geometry comes from 2x16B broadcast loads
// per unit instead of ~70 VALU ops recomputed per chunk.
__global__ __launch_bounds__(576)
void im2col_k5(const ushort* __restrict__ xt,
               const int* __restrict__ geo,
               ushort* __restrict__ colg) {
    __shared__ __align__(16) ushort tb[36 * TSTR_];   // 37440 B

    const int tid  = threadIdx.x;
    const int lane = tid & 63;
    const int wv   = tid >> 6;            // 0..8
    const int bid  = (int)blockIdx.x;
    const int chI  = bid & 7;             // chunk == XCD slot
    const int pbk  = bid >> 3;            // 0..479 pixel-block
    const int pb   = pbk * PT2_;
    const int b    = pb / HW_;
    const ushort* xtb = xt + (long)b * HW_ * CH_;
    ushort* cgo = colg + (long)pbk * (NCHK_ * COLW_) + (long)chI * COLW_;

    const int sseg = lane & 3;
    const int qd   = lane >> 2;
    const int cb0  = chI * CPC_ + sseg * 8;

    int   coff[4][4];
    float cwgt[4][4];
    int   ldst[4];
    #pragma unroll
    for (int g = 0; g < 4; ++g) {
        int pr = g * 144 + wv * 16 + qd;   // bijective over 0..575
        int px = pr & 63, kt = pr >> 6;
        const int* gp = geo + ((long)(pb + px) * K2_ + kt) * 8;
        int4   co = *(const int4*)(gp);        // broadcast across 4-lane cluster
        float4 wg = *(const float4*)(gp + 4);
        coff[g][0] = co.x + cb0;  cwgt[g][0] = wg.x;
        coff[g][1] = co.y + cb0;  cwgt[g][1] = wg.y;
        coff[g][2] = co.z + cb0;  cwgt[g][2] = wg.z;
        coff[g][3] = co.w + cb0;  cwgt[g][3] = wg.w;
        ldst[g] = (kt * 4 + sseg) * TSTR_ + px * 8;   // transpose-buffer slot
    }

    // phase 1: 16 coalesced gathers -> blend -> 4 LDS writes
    bf16x8 d[4][4];
    #pragma unroll
    for (int g = 0; g < 4; ++g)
        #pragma unroll
        for (int c = 0; c < 4; ++c)
            d[g][c] = *(const bf16x8*)(xtb + coff[g][c]);
    #pragma unroll
    for (int g = 0; g < 4; ++g) {
        float a8[8];
        #pragma unroll
        for (int j = 0; j < 8; ++j) a8[j] = 0.f;
        #pragma unroll
        for (int c = 0; c < 4; ++c) {
            float wgt = cwgt[g][c];
            #pragma unroll
            for (int j = 0; j < 8; ++j)
                a8[j] = fmaf(wgt, bf2f((ushort)d[g][c][j]), a8[j]);
        }
        bf16x8 o;
        #pragma unroll
        for (int j = 0; j < 8; ++j) o[j] = (short)f2bf(a8[j]);
        *(bf16x8*)(&tb[ldst[g]]) = o;
    }
    __syncthreads();

    // phase 2: granule-major re-read (linear b128) -> 1KB-contiguous stores
    #pragma unroll
    for (int g = 0; g < 4; ++g) {
        const int G = g * 9 + wv;          // 0..35
        bf16x8 o = *(const bf16x8*)(&tb[G * TSTR_ + lane * 8]);
        *(bf16x8*)(cgo + (G * 64 + lane) * 8) = o;
    }
}

// ======== v17b: PT=128 GEMM — deep per-chunk compute covers stage ========
__global__ __launch_bounds__(576, 1)
void conv_gemm5(const float* __restrict__ x,
                const ushort* __restrict__ colg,
                const ushort* __restrict__ wp2,
                const float* __restrict__ bias,
                float* __restrict__ out) {
    __shared__ __align__(16) ushort colL[4 * COLW_];   // 147456 B

    const int tid  = threadIdx.x;
    const int lane = tid & 63;
    const int wv   = tid >> 6;            // 0..8
    const int l15  = lane & 15;
    const int l16  = lane >> 4;
    const int bid  = (int)blockIdx.x;     // 0..239 (identity; no straddle)
    const int pb   = bid * PT5_;
    const int b    = pb / HW_;
    const int hw0  = pb % HW_;
    const long xb  = (long)b * CH_ * HW_;
    const long pbk64 = (long)bid * 2;     // two 64px col blocks

    f32x4 acc[2][8];
    #pragma unroll
    for (int m = 0; m < 2; ++m)
        #pragma unroll
        for (int n = 0; n < 8; ++n)
            acc[m][n] = (f32x4)(0.f);

    const int rg0 = wv * 2;
    const int mg  = wv * 32;

    auto STAGE = [&](int chI, int bufi) {
        #pragma unroll
        for (int hf = 0; hf < 2; ++hf) {
            const ushort* src = colg + ((pbk64 + hf) * NCHK_ + chI) * COLW_;
            ushort* dst = colL + (bufi * 2 + hf) * COLW_;
            #pragma unroll
            for (int i = 0; i < 4; ++i) {
                const int go = (wv * 4 + i) * 512;
                gld_lds16(src + go + lane * 8, dst + go);
            }
        }
    };
    auto COMPUTE = [&](int bufi, int chI) {
        if (wv < 8) {
            const ushort* wbase = wp2 + (((long)rg0 * NKST_ + chI * K2_) << 9) + (lane << 3);
            const long rstep = (long)NKST_ << 9;
            bf16x8 a0 = *(const bf16x8*)(wbase);
            bf16x8 a1 = *(const bf16x8*)(wbase + rstep);
            #pragma unroll
            for (int ks = 0; ks < K2_; ++ks) {
                bf16x8 a0n, a1n;
                if (ks < K2_ - 1) {                     // prefetch next ks
                    a0n = *(const bf16x8*)(wbase + ((ks + 1) << 9));
                    a1n = *(const bf16x8*)(wbase + rstep + ((ks + 1) << 9));
                }
                const ushort* cb0 = &colL[(bufi * 2) * COLW_ + ((ks * 4 + l16) * 64 + l15) * 8];
                const ushort* cb1 = cb0 + COLW_;
                bf16x8 b0 = *(const bf16x8*)(cb0);
                bf16x8 b1 = *(const bf16x8*)(cb0 + 128);
                bf16x8 b2 = *(const bf16x8*)(cb0 + 256);
                bf16x8 b3 = *(const bf16x8*)(cb0 + 384);
                bf16x8 b4 = *(const bf16x8*)(cb1);
                bf16x8 b5 = *(const bf16x8*)(cb1 + 128);
                bf16x8 b6 = *(const bf16x8*)(cb1 + 256);
                bf16x8 b7 = *(const bf16x8*)(cb1 + 384);
                __builtin_amdgcn_s_setprio(1);
                acc[0][0] = __builtin_amdgcn_mfma_f32_16x16x32_bf16(a0, b0, acc[0][0], 0, 0, 0);
                acc[0][1] = __builtin_amdgcn_mfma_f32_16x16x32_bf16(a0, b1, acc[0][1], 0, 0, 0);
                acc[0][2] = __builtin_amdgcn_mfma_f32_16x16x32_bf16(a0, b2, acc[0][2], 0, 0, 0);
                acc[0][3] = __builtin_amdgcn_mfma_f32_16x16x32_bf16(a0, b3, acc[0][3], 0, 0, 0);
                acc[0][4] = __builtin_amdgcn_mfma_f32_16x16x32_bf16(a0, b4, acc[0][4], 0, 0, 0);
                acc[0][5] = __builtin_amdgcn_mfma_f32_16x16x32_bf16(a0, b5, acc[0][5], 0, 0, 0);
                acc[0][6] = __builtin_amdgcn_mfma_f32_16x16x32_bf16(a0, b6, acc[0][6], 0, 0, 0);
                acc[0][7] = __builtin_amdgcn_mfma_f32_16x16x32_bf16(a0, b7, acc[0][7], 0, 0, 0);
                acc[1][0] = __builtin_amdgcn_mfma_f32_16x16x32_bf16(a1, b0, acc[1][0], 0, 0, 0);
                acc[1][1] = __builtin_amdgcn_mfma_f32_16x16x32_bf16(a1, b1, acc[1][1], 0, 0, 0);
                acc[1][2] = __builtin_amdgcn_mfma_f32_16x16x32_bf16(a1, b2, acc[1][2], 0, 0, 0);
                acc[1][3] = __builtin_amdgcn_mfma_f32_16x16x32_bf16(a1, b3, acc[1][3], 0, 0, 0);
                acc[1][4] = __builtin_amdgcn_mfma_f32_16x16x32_bf16(a1, b4, acc[1][4], 0, 0, 0);
                acc[1][5] = __builtin_amdgcn_mfma_f32_16x16x32_bf16(a1, b5, acc[1][5], 0, 0, 0);
                acc[1][6] = __builtin_amdgcn_mfma_f32_16x16x32_bf16(a1, b6, acc[1][6], 0, 0, 0);
                acc[1][7] = __builtin_amdgcn_mfma_f32_16x16x32_bf16(a1, b7, acc[1][7], 0, 0, 0);
                __builtin_amdgcn_s_setprio(0);
                if (ks < K2_ - 1) { a0 = a0n; a1 = a1n; }
            }
        }
    };

    STAGE(0, 0);
    __syncthreads();                       // buf0 ready
    for (int chI = 0; chI < NCHK_; ++chI) {
        const int cur = chI & 1, nxt = cur ^ 1;
        if (chI < NCHK_ - 1) STAGE(chI + 1, nxt);   // covered by 1380cy compute
        COMPUTE(cur, chI);
        __syncthreads();
    }

    if (wv < 8) {
        #pragma unroll
        for (int m = 0; m < 2; ++m)
            #pragma unroll
            for (int n = 0; n < 8; ++n)
                #pragma unroll
                for (int r = 0; r < 4; ++r) {
                    int o  = mg + m * 16 + l16 * 4 + r;
                    int hw = hw0 + n * 16 + l15;
                    long oi = xb + (long)o * HW_ + hw;
                    out[oi] = acc[m][n][r] + bias[o] + x[oi];
                }
    }
}

// ======== v11 (proven 140 us) — mid-tier if ws can't hold col+geo ========
__global__ __launch_bounds__(576)
void conv_mfma11(const float* __restrict__ x,
                 const ushort* __restrict__ xt,
                 const ushort* __restrict__ wp2,
                 const float* __restrict__ prob,
                 const float* __restrict__ table,
                 const float* __restrict__ bias,
                 float* __restrict__ out) {
    __shared__ __align__(16) ushort col[2][PT2_ * LSTR_];   // 75776 B
    __shared__ float off_l[PT2_ * 18];
    __shared__ float m_l[PT2_];

    const int tid  = threadIdx.x;
    const int lane = tid & 63;
    const int wv   = tid >> 6;
    const int l15  = lane & 15;
    const int l16  = lane >> 4;
    const int bid  = (int)blockIdx.x;
    const int bswz = (bid & 7) * (NBLK_ / 8) + (bid >> 3);
    const int pb   = bswz * PT2_;
    const int b    = pb / HW_;
    const int hw0  = pb % HW_;
    const long xb  = (long)b * CH_ * HW_;
    const ushort* xtb = xt + (long)b * HW_ * CH_;

    if (tid < PT2_) {
        const int px = tid;
        const int hw = hw0 + px;
        const float* pr = prob + (long)b * A_ * HW_ + hw;
        float v0 = -1e30f, v1 = -1e30f, v2 = -1e30f;
        int   i0 = 0, i1 = 0, i2 = 0;
        #pragma unroll 4
        for (int a = 0; a < A_; ++a) {
            float v = pr[(long)a * HW_];
            if (v > v0)      { v2=v1; i2=i1; v1=v0; i1=i0; v0=v; i0=a; }
            else if (v > v1) { v2=v1; i2=i1; v1=v;  i1=a; }
            else if (v > v2) { v2=v;  i2=a; }
        }
        float e1 = expf(v1 - v0), e2 = expf(v2 - v0);
        float inv = 1.0f / (1.0f + e1 + e2);
        float s0 = inv, s1 = e1*inv, s2 = e2*inv;
        float hard = (v0 > 0.5f) ? 1.0f : 0.0f;
        m_l[px] = v0;
        const float* t0 = table + ((long)i0 * 18) * HW_ + hw;
        const float* t1 = table + ((long)i1 * 18) * HW_ + hw;
        const float* t2 = table + ((long)i2 * 18) * HW_ + hw;
        #pragma unroll
        for (int c = 0; c < 18; ++c) {
            float o = s0 * t0[(long)c * HW_] + s1 * t1[(long)c * HW_] + s2 * t2[(long)c * HW_];
            off_l[px * 18 + c] = o * hard;
        }
    }
    __syncthreads();

    const int sseg = lane & 3;
    const int qd   = lane >> 2;
    int   coff[4][4];
    float cwgt[4][4];
    int   dsto[4];
    #pragma unroll
    for (int g = 0; g < 4; ++g) {
        int pr = g * 144 + wv * 16 + qd;
        int px = pr & 63, kt = pr >> 6;
        int hw = hw0 + px;
        int h  = hw / W_, w_ = hw % W_;
        float m    = m_l[px];
        float offh = off_l[px * 18 + 2*kt];
        float offw = off_l[px * 18 + 2*kt + 1];
        float py  = (float)(h  + (kt / 3 - 1)) + offh;
        float pxf = (float)(w_ + (kt % 3 - 1)) + offw;
        float y0f = floorf(py), x0f = floorf(pxf);
        float dy = py - y0f,   dx = pxf - x0f;
        int y0 = (int)y0f, x0i = (int)x0f;
        int y1 = y0 + 1,   x1  = x0i + 1;
        float vy0 = (y0  >= 0 && y0  < H_) ? 1.f : 0.f;
        float vy1 = (y1  >= 0 && y1  < H_) ? 1.f : 0.f;
        float vx0 = (x0i >= 0 && x0i < W_) ? 1.f : 0.f;
        float vx1 = (x1  >= 0 && x1  < W_) ? 1.f : 0.f;
        int cy0 = min(max(y0, 0),  H_-1), cy1 = min(max(y1, 0), H_-1);
        int cx0 = min(max(x0i, 0), W_-1), cx1 = min(max(x1, 0), W_-1);
        coff[g][0] = (cy0*W_ + cx0) * CH_;  cwgt[g][0] = (1.f-dy)*(1.f-dx)*vy0*vx0*m;
        coff[g][1] = (cy0*W_ + cx1) * CH_;  cwgt[g][1] = (1.f-dy)*dx      *vy0*vx1*m;
        coff[g][2] = (cy1*W_ + cx0) * CH_;  cwgt[g][2] = dy      *(1.f-dx)*vy1*vx0*m;
        coff[g][3] = (cy1*W_ + cx1) * CH_;  cwgt[g][3] = dy      *dx      *vy1*vx1*m;
        dsto[g] = px * LSTR_ + kt * CPC_ + sseg * 8;
    }

    f32x4 acc[2][4];
    #pragma unroll
    for (int m = 0; m < 2; ++m)
        #pragma unroll
        for (int n = 0; n < 4; ++n)
            acc[m][n] = (f32x4)(0.f);

    const int rg0 = wv * 2;
    const int mg  = wv * 32;

    bf16x8 d[2][4];

    auto LOADpair = [&](int chI, int g0) {
        const int cb0 = chI * CPC_ + sseg * 8;
        #pragma unroll
        for (int gg = 0; gg < 2; ++gg)
            #pragma unroll
            for (int c = 0; c < 4; ++c)
                d[gg][c] = *(const bf16x8*)(xtb + coff[g0 + gg][c] + cb0);
    };
    auto WRITEpair = [&](int bufi, int g0) {
        #pragma unroll
        for (int gg = 0; gg < 2; ++gg) {
            float a8[8];
            #pragma unroll
            for (int j = 0; j < 8; ++j) a8[j] = 0.f;
            #pragma unroll
            for (int c = 0; c < 4; ++c) {
                float wgt = cwgt[g0 + gg][c];
                #pragma unroll
                for (int j = 0; j < 8; ++j)
                    a8[j] = fmaf(wgt, bf2f((ushort)d[gg][c][j]), a8[j]);
            }
            bf16x8 o;
            #pragma unroll
            for (int j = 0; j < 8; ++j) o[j] = (short)f2bf(a8[j]);
            *(bf16x8*)(&col[bufi][dsto[g0 + gg]]) = o;
        }
    };
    auto COMPUTEhalf = [&](int bufi, int chI, int ks0, int ks1) {
        if (wv < 8) {
            for (int ks = ks0; ks < ks1; ++ks) {
                const int kst = chI * K2_ + ks;
                const ushort* wr = wp2 + (((long)rg0 * NKST_ + kst) << 9) + (lane << 3);
                bf16x8 a0 = *(const bf16x8*)(wr);
                bf16x8 a1 = *(const bf16x8*)(wr + (1l * NKST_ << 9));
                const ushort* cb = &col[bufi][l15 * LSTR_ + ks * 32 + 8 * l16];
                bf16x8 b0 = *(const bf16x8*)(cb);
                bf16x8 b1 = *(const bf16x8*)(cb + 16 * LSTR_);
                bf16x8 b2 = *(const bf16x8*)(cb + 32 * LSTR_);
                bf16x8 b3 = *(const bf16x8*)(cb + 48 * LSTR_);
                __builtin_amdgcn_s_setprio(1);
                acc[0][0] = __builtin_amdgcn_mfma_f32_16x16x32_bf16(a0, b0, acc[0][0], 0, 0, 0);
                acc[0][1] = __builtin_amdgcn_mfma_f32_16x16x32_bf16(a0, b1, acc[0][1], 0, 0, 0);
                acc[0][2] = __builtin_amdgcn_mfma_f32_16x16x32_bf16(a0, b2, acc[0][2], 0, 0, 0);
                acc[0][3] = __builtin_amdgcn_mfma_f32_16x16x32_bf16(a0, b3, acc[0][3], 0, 0, 0);
                acc[1][0] = __builtin_amdgcn_mfma_f32_16x16x32_bf16(a1, b0, acc[1][0], 0, 0, 0);
                acc[1][1] = __builtin_amdgcn_mfma_f32_16x16x32_bf16(a1, b1, acc[1][1], 0, 0, 0);
                acc[1][2] = __builtin_amdgcn_mfma_f32_16x16x32_bf16(a1, b2, acc[1][2], 0, 0, 0);
                acc[1][3] = __builtin_amdgcn_mfma_f32_16x16x32_bf16(a1, b3, acc[1][3], 0, 0, 0);
                __builtin_amdgcn_s_setprio(0);
            }
        }
    };

    LOADpair(0, 0); WRITEpair(0, 0);
    LOADpair(0, 2); WRITEpair(0, 2);
    __syncthreads();

    for (int chI = 0; chI < NCHK_; ++chI) {
        const int cur = chI & 1, nxt = cur ^ 1;
        const bool pf = (chI < NCHK_ - 1);
        if (pf) LOADpair(chI + 1, 0);
        COMPUTEhalf(cur, chI, 0, 4);
        if (pf) { WRITEpair(nxt, 0); LOADpair(chI + 1, 2); }
        COMPUTEhalf(cur, chI, 4, 9);
        if (pf) WRITEpair(nxt, 2);
        __syncthreads();
    }

    if (wv < 8) {
        #pragma unroll
        for (int m = 0; m < 2; ++m)
            #pragma unroll
            for (int n = 0; n < 4; ++n)
                #pragma unroll
                for (int r = 0; r < 4; ++r) {
                    int o  = mg + m * 16 + l16 * 4 + r;
                    int hw = hw0 + n * 16 + l15;
                    long oi = xb + (long)o * HW_ + hw;
                    out[oi] = acc[m][n][r] + bias[o] + x[oi];
                }
    }
}

// ======== v2 fallback (used if ws too small) ========
__global__ __launch_bounds__(576)
void conv_mfma2(const float* __restrict__ x,
                const ushort* __restrict__ wp,
                const float* __restrict__ bias,
                const float* __restrict__ m_arr,
                const float* __restrict__ off_arr,
                float* __restrict__ out) {
    __shared__ __align__(16) ushort col[PT2_ * LSTR_];

    const int tid  = threadIdx.x;
    const int lane = tid & 63;
    const int wv   = tid >> 6;
    const int l15  = lane & 15;
    const int l16  = lane >> 4;
    const int pb   = blockIdx.x * PT2_;
    const int b    = pb / HW_;
    const int hw0  = pb % HW_;
    const long xb  = (long)b * CH_ * HW_;

    int   id0, id1, id2, id3;
    float wg0, wg1, wg2, wg3;
    {
        int px = lane, kt = wv;
        int hw = hw0 + px;
        int h  = hw / W_, w_ = hw % W_;
        int pix = b * HW_ + hw;
        float m    = m_arr[pix];
        float offh = off_arr[(long)pix * 18 + 2*kt];
        float offw = off_arr[(long)pix * 18 + 2*kt + 1];
        float py = (float)(h  + (kt / 3 - 1)) + offh;
        float px_= (float)(w_ + (kt % 3 - 1)) + offw;
        float y0f = floorf(py), x0f = floorf(px_);
        float dy = py - y0f,   dx = px_ - x0f;
        int y0 = (int)y0f, x0 = (int)x0f;
        int y1 = y0 + 1,   x1 = x0 + 1;
        float vy0 = (y0 >= 0 && y0 < H_) ? 1.f : 0.f;
        float vy1 = (y1 >= 0 && y1 < H_) ? 1.f : 0.f;
        float vx0 = (x0 >= 0 && x0 < W_) ? 1.f : 0.f;
        float vx1 = (x1 >= 0 && x1 < W_) ? 1.f : 0.f;
        int cy0 = min(max(y0, 0), H_-1), cy1 = min(max(y1, 0), H_-1);
        int cx0 = min(max(x0, 0), W_-1), cx1 = min(max(x1, 0), W_-1);
        id0 = cy0*W_ + cx0;  wg0 = (1.f-dy)*(1.f-dx)*vy0*vx0*m;
        id1 = cy0*W_ + cx1;  wg1 = (1.f-dy)*dx      *vy0*vx1*m;
        id2 = cy1*W_ + cx0;  wg2 = dy      *(1.f-dx)*vy1*vx0*m;
        id3 = cy1*W_ + cx1;  wg3 = dy      *dx      *vy1*vx1*m;
    }

    f32x4 acc[4][2];
    #pragma unroll
    for (int m = 0; m < 4; ++m)
        #pragma unroll
        for (int n = 0; n < 2; ++n)
            acc[m][n] = (f32x4)(0.f);

    const int mg = (wv & 3) * 64;
    const int pg = (wv >> 2) * 32;

    for (int chI = 0; chI < NCHK_; ++chI) {
        __syncthreads();
        {
            const int c0 = chI * CPC_;
            ushort* dst = &col[lane * LSTR_ + wv * CPC_];
            #pragma unroll
            for (int c8 = 0; c8 < 4; ++c8) {
                bf16x8 pk;
                #pragma unroll
                for (int j = 0; j < 8; ++j) {
                    const float* xs = x + xb + (long)(c0 + c8*8 + j) * HW_;
                    float v = wg0 * xs[id0] + wg1 * xs[id1]
                            + wg2 * xs[id2] + wg3 * xs[id3];
                    pk[j] = (short)f2bf(v);
                }
                *(bf16x8*)(dst + c8 * 8) = pk;
            }
        }
        __syncthreads();
        if (wv < 8) {
            #pragma unroll
            for (int ks = 0; ks < K2_; ++ks) {
                const int kg = chI * KC_ + ks * 32 + 8 * l16;
                const ushort* wr = wp + (long)(mg + l15) * KTOT_ + kg;
                bf16x8 a0 = *(const bf16x8*)(wr);
                bf16x8 a1 = *(const bf16x8*)(wr + 16 * KTOT_);
                bf16x8 a2 = *(const bf16x8*)(wr + 32 * KTOT_);
                bf16x8 a3 = *(const bf16x8*)(wr + 48 * KTOT_);
                const ushort* cb = &col[(pg + l15) * LSTR_ + ks * 32 + 8 * l16];
                bf16x8 b0 = *(const bf16x8*)(cb);
                bf16x8 b1 = *(const bf16x8*)(cb + 16 * LSTR_);
                acc[0][0] = __builtin_amdgcn_mfma_f32_16x16x32_bf16(a0, b0, acc[0][0], 0, 0, 0);
                acc[0][1] = __builtin_amdgcn_mfma_f32_16x16x32_bf16(a0, b1, acc[0][1], 0, 0, 0);
                acc[1][0] = __builtin_amdgcn_mfma_f32_16x16x32_bf16(a1, b0, acc[1][0], 0, 0, 0);
                acc[1][1] = __builtin_amdgcn_mfma_f32_16x16x32_bf16(a1, b1, acc[1][1], 0, 0, 0);
                acc[2][0] = __builtin_amdgcn_mfma_f32_16x16x32_bf16(a2, b0, acc[2][0], 0, 0, 0);
                acc[2][1] = __builtin_amdgcn_mfma_f32_16x16x32_bf16(a2, b1, acc[2][1], 0, 0, 0);
                acc[3][0] = __builtin_amdgcn_mfma_f32_16x16x32_bf16(a3, b0, acc[3][0], 0, 0, 0);
                acc[3][1] = __builtin_amdgcn_mfma_f32_16x16x32_bf16(a3, b1, acc[3][1], 0, 0, 0);
            }
        }
    }

    if (wv < 8) {
        #pragma unroll
        for (int m = 0; m < 4; ++m)
            #pragma unroll
            for (int n = 0; n < 2; ++n)
                #pragma unroll
                for (int r = 0; r < 4; ++r) {
                    int o  = mg + m * 16 + l16 * 4 + r;
                    int hw = hw0 + pg + n * 16 + l15;
                    long oi = xb + (long)o * HW_ + hw;
                    out[oi] = acc[m][n][r] + bias[o] + x[oi];
                }
    }
}

extern "C" void kernel_launch(void* const* d_in, const int* in_sizes, int n_in,
                              void* d_out, int out_size, void* d_ws, size_t ws_size,
                              hipStream_t stream) {
    const float* x      = (const float*)d_in[0];
    const float* prob   = (const float*)d_in[1];
    const float* table  = (const float*)d_in[2];
    const float* weight = (const float*)d_in[3];
    const float* bias   = (const float*)d_in[4];
    float* out = (float*)d_out;

    const size_t wp_bytes  = (size_t)CH_ * KTOT_ * 2;          // 1,179,648
    const size_t m_bytes   = (size_t)NPIX_ * 4;                // 122,880
    const size_t off_bytes = (size_t)NPIX_ * 18 * 4;           // 2,211,840
    const size_t xt_bytes  = (size_t)NPIX_ * CH_ * 2;          // 15,728,640
    const size_t col_bytes = (size_t)NBLK_ * NCHK_ * COLB_;    // 141,557,760
    const size_t geo_bytes = (size_t)NPIX_ * K2_ * 32;         // 8,847,360

    ushort* wp_ws  = (ushort*)d_ws;
    float*  m_ws   = (float*)((char*)d_ws + wp_bytes);
    float*  off_ws = (float*)((char*)d_ws + wp_bytes + m_bytes);
    ushort* xt_ws  = (ushort*)((char*)d_ws + wp_bytes + m_bytes + off_bytes);
    ushort* col_ws = (ushort*)((char*)d_ws + wp_bytes + m_bytes + off_bytes + xt_bytes);
    int*    geo_ws = (int*)((char*)d_ws + wp_bytes + m_bytes + off_bytes + xt_bytes + col_bytes);

    const size_t need_v11 = wp_bytes + m_bytes + off_bytes + xt_bytes;
    const size_t need_v18 = need_v11 + col_bytes + geo_bytes;

    if (ws_size >= need_v18) {
        prep_weight2<<<(CH_ * KTOT_ + 255) / 256, 256, 0, stream>>>(weight, wp_ws);
        prep_xt<<<(HW_ / 128) * 4 * B_, 256, 0, stream>>>(x, xt_ws);
        gating_geo<<<NPIX_ / 256, 256, 0, stream>>>(prob, table, geo_ws);
        im2col_k5<<<NBLK_ * NCHK_, 576, 0, stream>>>(xt_ws, geo_ws, col_ws);
        conv_gemm5<<<NB5_, 576, 0, stream>>>(x, col_ws, wp_ws, bias, out);
    } else if (ws_size >= need_v11) {
        prep_weight2<<<(CH_ * KTOT_ + 255) / 256, 256, 0, stream>>>(weight, wp_ws);
        prep_xt<<<(HW_ / 128) * 4 * B_, 256, 0, stream>>>(x, xt_ws);
        conv_mfma11<<<NBLK_, 576, 0, stream>>>(x, xt_ws, wp_ws, prob, table, bias, out);
    } else {
        gating_kernel<<<NPIX_ / 256, 256, 0, stream>>>(prob, table, m_ws, off_ws);
        prep_weight<<<(CH_ * KTOT_ + 255) / 256, 256, 0, stream>>>(weight, wp_ws);
        conv_mfma2<<<NPIX_ / PT2_, 576, 0, stream>>>(x, wp_ws, bias, m_ws, off_ws, out);
    }
}

// Round 8
// 149.217 us; speedup vs baseline: 1.0539x; 1.0539x over previous
//
#include <hip/hip_runtime.h>
#include <math.h>

#define B_    4
#define CH_   256
#define H_    48
#define W_    160
#define A_    36
#define K2_   9
#define HW_   (H_*W_)        // 7680
#define NPIX_ (B_*HW_)       // 30720
#define KTOT_ (CH_*K2_)      // 2304
#define CPC_  32             // channels per chunk
#define KC_   (CPC_*K2_)     // 288 k' per chunk
#define NCHK_ (CH_/CPC_)     // 8
#define NKST_ (KTOT_/32)     // 72 k-steps of 32
#define LSTR_ 296            // LDS row stride (ushort) for v11/v2 paths
#define PT2_  64             // pixel tile (col image granularity)
#define NBLK_ (NPIX_/PT2_)   // 480 col pixel-blocks
#define COLB_ 36864          // bytes per (64px-block,chunk) col image: 36 gran*64px*16B
#define COLW_ (COLB_/2)      // 18432 ushorts
#define PT5_  128            // GEMM pixel tile
#define NB5_  (NPIX_/PT5_)   // 240 GEMM blocks
#define TSTR_ 520            // im2col LDS granule stride (ushorts) = 1040B (pad)

typedef __attribute__((ext_vector_type(8))) short bf16x8;
typedef __attribute__((ext_vector_type(4))) float f32x4;

__device__ inline ushort f2bf(float f) {
    union { float f; unsigned u; } c; c.f = f;
    unsigned r = c.u + 0x7FFFu + ((c.u >> 16) & 1u);
    return (ushort)(r >> 16);
}
__device__ inline float bf2f(ushort u) {
    union { unsigned u; float f; } c; c.u = (unsigned)u << 16; return c.f;
}

// async global->LDS, 16B per lane: LDS dest = wave-uniform base + lane*16
__device__ inline void gld_lds16(const ushort* g, ushort* l) {
    __builtin_amdgcn_global_load_lds(
        (const __attribute__((address_space(1))) unsigned int*)(g),
        (__attribute__((address_space(3))) unsigned int*)(l),
        16, 0, 0);
}

// ---------------- weight fp32 -> bf16, MFMA-fragment-ordered ----------------
__global__ __launch_bounds__(256)
void prep_weight2(const float* __restrict__ w, ushort* __restrict__ wp2) {
    int t = blockIdx.x * 256 + threadIdx.x;
    if (t >= CH_ * KTOT_) return;
    int j    = t & 7;
    int lane = (t >> 3) & 63;
    int kk   = t >> 9;             // 0..1151
    int kst  = kk % NKST_;
    int rg   = kk / NKST_;         // 0..15
    int row  = rg * 16 + (lane & 15);
    int kq   = kst * 32 + (lane >> 4) * 8 + j;   // k'
    int chunk = kq / KC_, r = kq % KC_;
    int tap = r / CPC_, ci = r % CPC_;
    int c = chunk * CPC_ + ci;
    wp2[t] = f2bf(w[(row * CH_ + c) * K2_ + tap]);
}

// ---------------- weight fp32 -> bf16, K-permuted (fallback layout) ----------
__global__ __launch_bounds__(256)
void prep_weight(const float* __restrict__ w, ushort* __restrict__ wp) {
    int t = blockIdx.x * 256 + threadIdx.x;
    if (t >= CH_ * KTOT_) return;
    int o  = t / KTOT_, kk = t % KTOT_;
    int chunk = kk / KC_, r = kk % KC_;
    int tap = r / CPC_, ci = r % CPC_;
    int c = chunk * CPC_ + ci;
    wp[t] = f2bf(w[(o * CH_ + c) * K2_ + tap]);
}

// ---------------- x [B,C,HW] f32 -> xt [B,HW,C] bf16 ----------------
__global__ __launch_bounds__(256)
void prep_xt(const float* __restrict__ x, ushort* __restrict__ xt) {
    int bid = blockIdx.x;
    int hwT = bid % (HW_ / 128);           // 60
    int rest = bid / (HW_ / 128);
    int cT = rest & 3;
    int b  = rest >> 2;
    int hw0 = hwT * 128, c0 = cT * 64;
    int tid = threadIdx.x;
    int u = tid & 7, s = tid >> 3;
    const float* xb = x + ((long)b * CH_ + c0 + u * 8) * HW_ + hw0 + s * 4;
    float4 L[8];
    #pragma unroll
    for (int i = 0; i < 8; ++i) L[i] = *(const float4*)(xb + (long)i * HW_);
    ushort* xo = xt + ((long)b * HW_ + hw0 + s * 4) * CH_ + c0 + u * 8;
    #pragma unroll
    for (int j = 0; j < 4; ++j) {
        bf16x8 o;
        #pragma unroll
        for (int i = 0; i < 8; ++i) {
            float f = (j == 0) ? L[i].x : (j == 1) ? L[i].y : (j == 2) ? L[i].z : L[i].w;
            o[i] = (short)f2bf(f);
        }
        *(bf16x8*)(xo + (long)j * CH_) = o;
    }
}

// ---------------- top-k gating + offset blend -> m, off (global) ----------
__global__ __launch_bounds__(256)
void gating_kernel(const float* __restrict__ prob,
                   const float* __restrict__ table,
                   float* __restrict__ m_out,
                   float* __restrict__ off_out) {
    int pix = blockIdx.x * 256 + threadIdx.x;
    if (pix >= NPIX_) return;
    int b  = pix / HW_;
    int hw = pix % HW_;
    const float* pr = prob + (long)b * A_ * HW_ + hw;

    float v0 = -1e30f, v1 = -1e30f, v2 = -1e30f;
    int   i0 = 0, i1 = 0, i2 = 0;
    #pragma unroll 4
    for (int a = 0; a < A_; ++a) {
        float v = pr[(long)a * HW_];
        if (v > v0)      { v2=v1; i2=i1; v1=v0; i1=i0; v0=v; i0=a; }
        else if (v > v1) { v2=v1; i2=i1; v1=v;  i1=a; }
        else if (v > v2) { v2=v;  i2=a; }
    }
    float e1 = expf(v1 - v0), e2 = expf(v2 - v0);
    float inv = 1.0f / (1.0f + e1 + e2);
    float s0 = inv, s1 = e1*inv, s2 = e2*inv;
    float hard = (v0 > 0.5f) ? 1.0f : 0.0f;

    m_out[pix] = v0;
    const float* t0 = table + ((long)i0 * 18) * HW_ + hw;
    const float* t1 = table + ((long)i1 * 18) * HW_ + hw;
    const float* t2 = table + ((long)i2 * 18) * HW_ + hw;
    float* op = off_out + (long)pix * 18;
    #pragma unroll
    for (int c = 0; c < 18; ++c) {
        float o = s0 * t0[(long)c * HW_] + s1 * t1[(long)c * HW_] + s2 * t2[(long)c * HW_];
        op[c] = o * hard;
    }
}

// ======== im2col_k4 (proven 54us, round-6 verbatim): coalesced both ends ====
__global__ __launch_bounds__(576)
void im2col_k4(const ushort* __restrict__ xt,
               const float* __restrict__ m_arr,
               const float* __restrict__ off_arr,
               ushort* __restrict__ colg) {
    __shared__ __align__(16) ushort tb[36 * TSTR_];   // 37440 B

    const int tid  = threadIdx.x;
    const int lane = tid & 63;
    const int wv   = tid >> 6;            // 0..8
    const int bid  = (int)blockIdx.x;
    const int chI  = bid & 7;             // chunk == XCD slot
    const int pbk  = bid >> 3;            // 0..479 pixel-block
    const int pb   = pbk * PT2_;
    const int b    = pb / HW_;
    const int hw0  = pb % HW_;
    const ushort* xtb = xt + (long)b * HW_ * CH_;
    ushort* cgo = colg + (long)pbk * (NCHK_ * COLW_) + (long)chI * COLW_;

    const int sseg = lane & 3;
    const int qd   = lane >> 2;
    const int cb0  = chI * CPC_ + sseg * 8;

    int   coff[4][4];
    float cwgt[4][4];
    int   ldst[4];
    #pragma unroll
    for (int g = 0; g < 4; ++g) {
        int pr = g * 144 + wv * 16 + qd;   // bijective over 0..575
        int px = pr & 63, kt = pr >> 6;
        int hw = hw0 + px;
        int pix = pb + px;
        int h  = hw / W_, w_ = hw % W_;
        float m    = m_arr[pix];
        float2 ohw = *(const float2*)(off_arr + (long)pix * 18 + 2 * kt);
        float py  = (float)(h  + (kt / 3 - 1)) + ohw.x;
        float pxf = (float)(w_ + (kt % 3 - 1)) + ohw.y;
        float y0f = floorf(py), x0f = floorf(pxf);
        float dy = py - y0f,   dx = pxf - x0f;
        int y0 = (int)y0f, x0i = (int)x0f;
        int y1 = y0 + 1,   x1  = x0i + 1;
        float vy0 = (y0  >= 0 && y0  < H_) ? 1.f : 0.f;
        float vy1 = (y1  >= 0 && y1  < H_) ? 1.f : 0.f;
        float vx0 = (x0i >= 0 && x0i < W_) ? 1.f : 0.f;
        float vx1 = (x1  >= 0 && x1  < W_) ? 1.f : 0.f;
        int cy0 = min(max(y0, 0),  H_-1), cy1 = min(max(y1, 0), H_-1);
        int cx0 = min(max(x0i, 0), W_-1), cx1 = min(max(x1, 0), W_-1);
        coff[g][0] = (cy0*W_ + cx0) * CH_ + cb0;  cwgt[g][0] = (1.f-dy)*(1.f-dx)*vy0*vx0*m;
        coff[g][1] = (cy0*W_ + cx1) * CH_ + cb0;  cwgt[g][1] = (1.f-dy)*dx      *vy0*vx1*m;
        coff[g][2] = (cy1*W_ + cx0) * CH_ + cb0;  cwgt[g][2] = dy      *(1.f-dx)*vy1*vx0*m;
        coff[g][3] = (cy1*W_ + cx1) * CH_ + cb0;  cwgt[g][3] = dy      *dx      *vy1*vx1*m;
        ldst[g] = (kt * 4 + sseg) * TSTR_ + px * 8;   // transpose-buffer slot
    }

    // phase 1: 16 coalesced gathers -> blend -> 4 LDS writes
    bf16x8 d[4][4];
    #pragma unroll
    for (int g = 0; g < 4; ++g)
        #pragma unroll
        for (int c = 0; c < 4; ++c)
            d[g][c] = *(const bf16x8*)(xtb + coff[g][c]);
    #pragma unroll
    for (int g = 0; g < 4; ++g) {
        float a8[8];
        #pragma unroll
        for (int j = 0; j < 8; ++j) a8[j] = 0.f;
        #pragma unroll
        for (int c = 0; c < 4; ++c) {
            float wgt = cwgt[g][c];
            #pragma unroll
            for (int j = 0; j < 8; ++j)
                a8[j] = fmaf(wgt, bf2f((ushort)d[g][c][j]), a8[j]);
        }
        bf16x8 o;
        #pragma unroll
        for (int j = 0; j < 8; ++j) o[j] = (short)f2bf(a8[j]);
        *(bf16x8*)(&tb[ldst[g]]) = o;
    }
    __syncthreads();

    // phase 2: granule-major re-read (linear b128) -> 1KB-contiguous stores
    #pragma unroll
    for (int g = 0; g < 4; ++g) {
        const int G = g * 9 + wv;          // 0..35
        bf16x8 o = *(const bf16x8*)(&tb[G * TSTR_ + lane * 8]);
        *(bf16x8*)(cgo + (G * 64 + lane) * 8) = o;
    }
}

// ======== v19: PT=128 GEMM with CORRECT vmcnt accounting ========
// gemm5's bug: per-chunk weight loads were issued AFTER the 16 staging
// gld_lds in the same vmcnt FIFO, so consuming the first weight forced
// s_waitcnt vmcnt(0) -> drained next-chunk staging at every compute start
// (round-4 disease in a new spot). Fix: load ALL 18 weight fragments to
// registers BEFORE issuing STAGE(chI+1); weights are then OLDER in the
// FIFO, so their wait is vmcnt(16) and the staging stays in flight under
// the whole ~1400cyc/SIMD of MFMA. sched_barrier pins the issue order.
__global__ __launch_bounds__(576, 1)
void conv_gemm6(const float* __restrict__ x,
                const ushort* __restrict__ colg,
                const ushort* __restrict__ wp2,
                const float* __restrict__ bias,
                float* __restrict__ out) {
    __shared__ __align__(16) ushort colL[4 * COLW_];   // 147456 B

    const int tid  = threadIdx.x;
    const int lane = tid & 63;
    const int wv   = tid >> 6;            // 0..8
    const int l15  = lane & 15;
    const int l16  = lane >> 4;
    const int bid  = (int)blockIdx.x;     // 0..239
    const int pb   = bid * PT5_;
    const int b    = pb / HW_;
    const int hw0  = pb % HW_;
    const long xb  = (long)b * CH_ * HW_;
    const long pbk64 = (long)bid * 2;     // two 64px col blocks

    f32x4 acc[2][8];
    #pragma unroll
    for (int m = 0; m < 2; ++m)
        #pragma unroll
        for (int n = 0; n < 8; ++n)
            acc[m][n] = (f32x4)(0.f);

    const int rg0 = wv * 2;
    const int mg  = wv * 32;

    auto STAGE = [&](int chI, int bufi) {
        #pragma unroll
        for (int hf = 0; hf < 2; ++hf) {
            const ushort* src = colg + ((pbk64 + hf) * NCHK_ + chI) * COLW_;
            ushort* dst = colL + (bufi * 2 + hf) * COLW_;
            #pragma unroll
            for (int i = 0; i < 4; ++i) {
                const int go = (wv * 4 + i) * 512;
                gld_lds16(src + go + lane * 8, dst + go);
            }
        }
    };

    STAGE(0, 0);
    __syncthreads();                       // buf0 ready
    for (int chI = 0; chI < NCHK_; ++chI) {
        const int cur = chI & 1, nxt = cur ^ 1;

        // (a) weight fragments for THIS chunk -> registers (oldest in FIFO)
        bf16x8 wA0[K2_], wA1[K2_];
        if (wv < 8) {
            const ushort* wbase = wp2 + (((long)rg0 * NKST_ + chI * K2_) << 9) + (lane << 3);
            const long rstep = (long)NKST_ << 9;
            #pragma unroll
            for (int ks = 0; ks < K2_; ++ks) {
                wA0[ks] = *(const bf16x8*)(wbase + ((long)ks << 9));
                wA1[ks] = *(const bf16x8*)(wbase + rstep + ((long)ks << 9));
            }
        }
        __builtin_amdgcn_sched_barrier(0); // pin: weights issue before staging

        // (b) next-chunk staging (newer in FIFO -> never drained by (c))
        if (chI < NCHK_ - 1) STAGE(chI + 1, nxt);

        // (c) compute: waits only on weights (vmcnt(16)) + LDS reads
        if (wv < 8) {
            #pragma unroll
            for (int ks = 0; ks < K2_; ++ks) {
                const ushort* cb0 = &colL[(cur * 2) * COLW_ + ((ks * 4 + l16) * 64 + l15) * 8];
                const ushort* cb1 = cb0 + COLW_;
                bf16x8 b0 = *(const bf16x8*)(cb0);
                bf16x8 b1 = *(const bf16x8*)(cb0 + 128);
                bf16x8 b2 = *(const bf16x8*)(cb0 + 256);
                bf16x8 b3 = *(const bf16x8*)(cb0 + 384);
                bf16x8 b4 = *(const bf16x8*)(cb1);
                bf16x8 b5 = *(const bf16x8*)(cb1 + 128);
                bf16x8 b6 = *(const bf16x8*)(cb1 + 256);
                bf16x8 b7 = *(const bf16x8*)(cb1 + 384);
                __builtin_amdgcn_s_setprio(1);
                acc[0][0] = __builtin_amdgcn_mfma_f32_16x16x32_bf16(wA0[ks], b0, acc[0][0], 0, 0, 0);
                acc[0][1] = __builtin_amdgcn_mfma_f32_16x16x32_bf16(wA0[ks], b1, acc[0][1], 0, 0, 0);
                acc[0][2] = __builtin_amdgcn_mfma_f32_16x16x32_bf16(wA0[ks], b2, acc[0][2], 0, 0, 0);
                acc[0][3] = __builtin_amdgcn_mfma_f32_16x16x32_bf16(wA0[ks], b3, acc[0][3], 0, 0, 0);
                acc[0][4] = __builtin_amdgcn_mfma_f32_16x16x32_bf16(wA0[ks], b4, acc[0][4], 0, 0, 0);
                acc[0][5] = __builtin_amdgcn_mfma_f32_16x16x32_bf16(wA0[ks], b5, acc[0][5], 0, 0, 0);
                acc[0][6] = __builtin_amdgcn_mfma_f32_16x16x32_bf16(wA0[ks], b6, acc[0][6], 0, 0, 0);
                acc[0][7] = __builtin_amdgcn_mfma_f32_16x16x32_bf16(wA0[ks], b7, acc[0][7], 0, 0, 0);
                acc[1][0] = __builtin_amdgcn_mfma_f32_16x16x32_bf16(wA1[ks], b0, acc[1][0], 0, 0, 0);
                acc[1][1] = __builtin_amdgcn_mfma_f32_16x16x32_bf16(wA1[ks], b1, acc[1][1], 0, 0, 0);
                acc[1][2] = __builtin_amdgcn_mfma_f32_16x16x32_bf16(wA1[ks], b2, acc[1][2], 0, 0, 0);
                acc[1][3] = __builtin_amdgcn_mfma_f32_16x16x32_bf16(wA1[ks], b3, acc[1][3], 0, 0, 0);
                acc[1][4] = __builtin_amdgcn_mfma_f32_16x16x32_bf16(wA1[ks], b4, acc[1][4], 0, 0, 0);
                acc[1][5] = __builtin_amdgcn_mfma_f32_16x16x32_bf16(wA1[ks], b5, acc[1][5], 0, 0, 0);
                acc[1][6] = __builtin_amdgcn_mfma_f32_16x16x32_bf16(wA1[ks], b6, acc[1][6], 0, 0, 0);
                acc[1][7] = __builtin_amdgcn_mfma_f32_16x16x32_bf16(wA1[ks], b7, acc[1][7], 0, 0, 0);
                __builtin_amdgcn_s_setprio(0);
            }
        }
        __syncthreads();                   // staging done (covered by MFMA)
    }

    if (wv < 8) {
        #pragma unroll
        for (int m = 0; m < 2; ++m)
            #pragma unroll
            for (int n = 0; n < 8; ++n)
                #pragma unroll
                for (int r = 0; r < 4; ++r) {
                    int o  = mg + m * 16 + l16 * 4 + r;
                    int hw = hw0 + n * 16 + l15;
                    long oi = xb + (long)o * HW_ + hw;
                    out[oi] = acc[m][n][r] + bias[o] + x[oi];
                }
    }
}

// ======== v11 (proven 140 us) — mid-tier if ws can't hold col ========
__global__ __launch_bounds__(576)
void conv_mfma11(const float* __restrict__ x,
                 const ushort* __restrict__ xt,
                 const ushort* __restrict__ wp2,
                 const float* __restrict__ prob,
                 const float* __restrict__ table,
                 const float* __restrict__ bias,
                 float* __restrict__ out) {
    __shared__ __align__(16) ushort col[2][PT2_ * LSTR_];   // 75776 B
    __shared__ float off_l[PT2_ * 18];
    __shared__ float m_l[PT2_];

    const int tid  = threadIdx.x;
    const int lane = tid & 63;
    const int wv   = tid >> 6;
    const int l15  = lane & 15;
    const int l16  = lane >> 4;
    const int bid  = (int)blockIdx.x;
    const int bswz = (bid & 7) * (NBLK_ / 8) + (bid >> 3);
    const int pb   = bswz * PT2_;
    const int b    = pb / HW_;
    const int hw0  = pb % HW_;
    const long xb  = (long)b * CH_ * HW_;
    const ushort* xtb = xt + (long)b * HW_ * CH_;

    if (tid < PT2_) {
        const int px = tid;
        const int hw = hw0 + px;
        const float* pr = prob + (long)b * A_ * HW_ + hw;
        float v0 = -1e30f, v1 = -1e30f, v2 = -1e30f;
        int   i0 = 0, i1 = 0, i2 = 0;
        #pragma unroll 4
        for (int a = 0; a < A_; ++a) {
            float v = pr[(long)a * HW_];
            if (v > v0)      { v2=v1; i2=i1; v1=v0; i1=i0; v0=v; i0=a; }
            else if (v > v1) { v2=v1; i2=i1; v1=v;  i1=a; }
            else if (v > v2) { v2=v;  i2=a; }
        }
        float e1 = expf(v1 - v0), e2 = expf(v2 - v0);
        float inv = 1.0f / (1.0f + e1 + e2);
        float s0 = inv, s1 = e1*inv, s2 = e2*inv;
        float hard = (v0 > 0.5f) ? 1.0f : 0.0f;
        m_l[px] = v0;
        const float* t0 = table + ((long)i0 * 18) * HW_ + hw;
        const float* t1 = table + ((long)i1 * 18) * HW_ + hw;
        const float* t2 = table + ((long)i2 * 18) * HW_ + hw;
        #pragma unroll
        for (int c = 0; c < 18; ++c) {
            float o = s0 * t0[(long)c * HW_] + s1 * t1[(long)c * HW_] + s2 * t2[(long)c * HW_];
            off_l[px * 18 + c] = o * hard;
        }
    }
    __syncthreads();

    const int sseg = lane & 3;
    const int qd   = lane >> 2;
    int   coff[4][4];
    float cwgt[4][4];
    int   dsto[4];
    #pragma unroll
    for (int g = 0; g < 4; ++g) {
        int pr = g * 144 + wv * 16 + qd;
        int px = pr & 63, kt = pr >> 6;
        int hw = hw0 + px;
        int h  = hw / W_, w_ = hw % W_;
        float m    = m_l[px];
        float offh = off_l[px * 18 + 2*kt];
        float offw = off_l[px * 18 + 2*kt + 1];
        float py  = (float)(h  + (kt / 3 - 1)) + offh;
        float pxf = (float)(w_ + (kt % 3 - 1)) + offw;
        float y0f = floorf(py), x0f = floorf(pxf);
        float dy = py - y0f,   dx = pxf - x0f;
        int y0 = (int)y0f, x0i = (int)x0f;
        int y1 = y0 + 1,   x1  = x0i + 1;
        float vy0 = (y0  >= 0 && y0  < H_) ? 1.f : 0.f;
        float vy1 = (y1  >= 0 && y1  < H_) ? 1.f : 0.f;
        float vx0 = (x0i >= 0 && x0i < W_) ? 1.f : 0.f;
        float vx1 = (x1  >= 0 && x1  < W_) ? 1.f : 0.f;
        int cy0 = min(max(y0, 0),  H_-1), cy1 = min(max(y1, 0), H_-1);
        int cx0 = min(max(x0i, 0), W_-1), cx1 = min(max(x1, 0), W_-1);
        coff[g][0] = (cy0*W_ + cx0) * CH_;  cwgt[g][0] = (1.f-dy)*(1.f-dx)*vy0*vx0*m;
        coff[g][1] = (cy0*W_ + cx1) * CH_;  cwgt[g][1] = (1.f-dy)*dx      *vy0*vx1*m;
        coff[g][2] = (cy1*W_ + cx0) * CH_;  cwgt[g][2] = dy      *(1.f-dx)*vy1*vx0*m;
        coff[g][3] = (cy1*W_ + cx1) * CH_;  cwgt[g][3] = dy      *dx      *vy1*vx1*m;
        dsto[g] = px * LSTR_ + kt * CPC_ + sseg * 8;
    }

    f32x4 acc[2][4];
    #pragma unroll
    for (int m = 0; m < 2; ++m)
        #pragma unroll
        for (int n = 0; n < 4; ++n)
            acc[m][n] = (f32x4)(0.f);

    const int rg0 = wv * 2;
    const int mg  = wv * 32;

    bf16x8 d[2][4];

    auto LOADpair = [&](int chI, int g0) {
        const int cb0 = chI * CPC_ + sseg * 8;
        #pragma unroll
        for (int gg = 0; gg < 2; ++gg)
            #pragma unroll
            for (int c = 0; c < 4; ++c)
                d[gg][c] = *(const bf16x8*)(xtb + coff[g0 + gg][c] + cb0);
    };
    auto WRITEpair = [&](int bufi, int g0) {
        #pragma unroll
        for (int gg = 0; gg < 2; ++gg) {
            float a8[8];
            #pragma unroll
            for (int j = 0; j < 8; ++j) a8[j] = 0.f;
            #pragma unroll
            for (int c = 0; c < 4; ++c) {
                float wgt = cwgt[g0 + gg][c];
                #pragma unroll
                for (int j = 0; j < 8; ++j)
                    a8[j] = fmaf(wgt, bf2f((ushort)d[gg][c][j]), a8[j]);
            }
            bf16x8 o;
            #pragma unroll
            for (int j = 0; j < 8; ++j) o[j] = (short)f2bf(a8[j]);
            *(bf16x8*)(&col[bufi][dsto[g0 + gg]]) = o;
        }
    };
    auto COMPUTEhalf = [&](int bufi, int chI, int ks0, int ks1) {
        if (wv < 8) {
            for (int ks = ks0; ks < ks1; ++ks) {
                const int kst = chI * K2_ + ks;
                const ushort* wr = wp2 + (((long)rg0 * NKST_ + kst) << 9) + (lane << 3);
                bf16x8 a0 = *(const bf16x8*)(wr);
                bf16x8 a1 = *(const bf16x8*)(wr + (1l * NKST_ << 9));
                const ushort* cb = &col[bufi][l15 * LSTR_ + ks * 32 + 8 * l16];
                bf16x8 b0 = *(const bf16x8*)(cb);
                bf16x8 b1 = *(const bf16x8*)(cb + 16 * LSTR_);
                bf16x8 b2 = *(const bf16x8*)(cb + 32 * LSTR_);
                bf16x8 b3 = *(const bf16x8*)(cb + 48 * LSTR_);
                __builtin_amdgcn_s_setprio(1);
                acc[0][0] = __builtin_amdgcn_mfma_f32_16x16x32_bf16(a0, b0, acc[0][0], 0, 0, 0);
                acc[0][1] = __builtin_amdgcn_mfma_f32_16x16x32_bf16(a0, b1, acc[0][1], 0, 0, 0);
                acc[0][2] = __builtin_amdgcn_mfma_f32_16x16x32_bf16(a0, b2, acc[0][2], 0, 0, 0);
                acc[0][3] = __builtin_amdgcn_mfma_f32_16x16x32_bf16(a0, b3, acc[0][3], 0, 0, 0);
                acc[1][0] = __builtin_amdgcn_mfma_f32_16x16x32_bf16(a1, b0, acc[1][0], 0, 0, 0);
                acc[1][1] = __builtin_amdgcn_mfma_f32_16x16x32_bf16(a1, b1, acc[1][1], 0, 0, 0);
                acc[1][2] = __builtin_amdgcn_mfma_f32_16x16x32_bf16(a1, b2, acc[1][2], 0, 0, 0);
                acc[1][3] = __builtin_amdgcn_mfma_f32_16x16x32_bf16(a1, b3, acc[1][3], 0, 0, 0);
                __builtin_amdgcn_s_setprio(0);
            }
        }
    };

    LOADpair(0, 0); WRITEpair(0, 0);
    LOADpair(0, 2); WRITEpair(0, 2);
    __syncthreads();

    for (int chI = 0; chI < NCHK_; ++chI) {
        const int cur = chI & 1, nxt = cur ^ 1;
        const bool pf = (chI < NCHK_ - 1);
        if (pf) LOADpair(chI + 1, 0);
        COMPUTEhalf(cur, chI, 0, 4);
        if (pf) { WRITEpair(nxt, 0); LOADpair(chI + 1, 2); }
        COMPUTEhalf(cur, chI, 4, 9);
        if (pf) WRITEpair(nxt, 2);
        __syncthreads();
    }

    if (wv < 8) {
        #pragma unroll
        for (int m = 0; m < 2; ++m)
            #pragma unroll
            for (int n = 0; n < 4; ++n)
                #pragma unroll
                for (int r = 0; r < 4; ++r) {
                    int o  = mg + m * 16 + l16 * 4 + r;
                    int hw = hw0 + n * 16 + l15;
                    long oi = xb + (long)o * HW_ + hw;
                    out[oi] = acc[m][n][r] + bias[o] + x[oi];
                }
    }
}

// ======== v2 fallback (used if ws too small) ========
__global__ __launch_bounds__(576)
void conv_mfma2(const float* __restrict__ x,
                const ushort* __restrict__ wp,
                const float* __restrict__ bias,
                const float* __restrict__ m_arr,
                const float* __restrict__ off_arr,
                float* __restrict__ out) {
    __shared__ __align__(16) ushort col[PT2_ * LSTR_];

    const int tid  = threadIdx.x;
    const int lane = tid & 63;
    const int wv   = tid >> 6;
    const int l15  = lane & 15;
    const int l16  = lane >> 4;
    const int pb   = blockIdx.x * PT2_;
    const int b    = pb / HW_;
    const int hw0  = pb % HW_;
    const long xb  = (long)b * CH_ * HW_;

    int   id0, id1, id2, id3;
    float wg0, wg1, wg2, wg3;
    {
        int px = lane, kt = wv;
        int hw = hw0 + px;
        int h  = hw / W_, w_ = hw % W_;
        int pix = b * HW_ + hw;
        float m    = m_arr[pix];
        float offh = off_arr[(long)pix * 18 + 2*kt];
        float offw = off_arr[(long)pix * 18 + 2*kt + 1];
        float py = (float)(h  + (kt / 3 - 1)) + offh;
        float px_= (float)(w_ + (kt % 3 - 1)) + offw;
        float y0f = floorf(py), x0f = floorf(px_);
        float dy = py - y0f,   dx = px_ - x0f;
        int y0 = (int)y0f, x0 = (int)x0f;
        int y1 = y0 + 1,   x1 = x0 + 1;
        float vy0 = (y0 >= 0 && y0 < H_) ? 1.f : 0.f;
        float vy1 = (y1 >= 0 && y1 < H_) ? 1.f : 0.f;
        float vx0 = (x0 >= 0 && x0 < W_) ? 1.f : 0.f;
        float vx1 = (x1 >= 0 && x1 < W_) ? 1.f : 0.f;
        int cy0 = min(max(y0, 0), H_-1), cy1 = min(max(y1, 0), H_-1);
        int cx0 = min(max(x0, 0), W_-1), cx1 = min(max(x1, 0), W_-1);
        id0 = cy0*W_ + cx0;  wg0 = (1.f-dy)*(1.f-dx)*vy0*vx0*m;
        id1 = cy0*W_ + cx1;  wg1 = (1.f-dy)*dx      *vy0*vx1*m;
        id2 = cy1*W_ + cx0;  wg2 = dy      *(1.f-dx)*vy1*vx0*m;
        id3 = cy1*W_ + cx1;  wg3 = dy      *dx      *vy1*vx1*m;
    }

    f32x4 acc[4][2];
    #pragma unroll
    for (int m = 0; m < 4; ++m)
        #pragma unroll
        for (int n = 0; n < 2; ++n)
            acc[m][n] = (f32x4)(0.f);

    const int mg = (wv & 3) * 64;
    const int pg = (wv >> 2) * 32;

    for (int chI = 0; chI < NCHK_; ++chI) {
        __syncthreads();
        {
            const int c0 = chI * CPC_;
            ushort* dst = &col[lane * LSTR_ + wv * CPC_];
            #pragma unroll
            for (int c8 = 0; c8 < 4; ++c8) {
                bf16x8 pk;
                #pragma unroll
                for (int j = 0; j < 8; ++j) {
                    const float* xs = x + xb + (long)(c0 + c8*8 + j) * HW_;
                    float v = wg0 * xs[id0] + wg1 * xs[id1]
                            + wg2 * xs[id2] + wg3 * xs[id3];
                    pk[j] = (short)f2bf(v);
                }
                *(bf16x8*)(dst + c8 * 8) = pk;
            }
        }
        __syncthreads();
        if (wv < 8) {
            #pragma unroll
            for (int ks = 0; ks < K2_; ++ks) {
                const int kg = chI * KC_ + ks * 32 + 8 * l16;
                const ushort* wr = wp + (long)(mg + l15) * KTOT_ + kg;
                bf16x8 a0 = *(const bf16x8*)(wr);
                bf16x8 a1 = *(const bf16x8*)(wr + 16 * KTOT_);
                bf16x8 a2 = *(const bf16x8*)(wr + 32 * KTOT_);
                bf16x8 a3 = *(const bf16x8*)(wr + 48 * KTOT_);
                const ushort* cb = &col[(pg + l15) * LSTR_ + ks * 32 + 8 * l16];
                bf16x8 b0 = *(const bf16x8*)(cb);
                bf16x8 b1 = *(const bf16x8*)(cb + 16 * LSTR_);
                acc[0][0] = __builtin_amdgcn_mfma_f32_16x16x32_bf16(a0, b0, acc[0][0], 0, 0, 0);
                acc[0][1] = __builtin_amdgcn_mfma_f32_16x16x32_bf16(a0, b1, acc[0][1], 0, 0, 0);
                acc[1][0] = __builtin_amdgcn_mfma_f32_16x16x32_bf16(a1, b0, acc[1][0], 0, 0, 0);
                acc[1][1] = __builtin_amdgcn_mfma_f32_16x16x32_bf16(a1, b1, acc[1][1], 0, 0, 0);
                acc[2][0] = __builtin_amdgcn_mfma_f32_16x16x32_bf16(a2, b0, acc[2][0], 0, 0, 0);
                acc[2][1] = __builtin_amdgcn_mfma_f32_16x16x32_bf16(a2, b1, acc[2][1], 0, 0, 0);
                acc[3][0] = __builtin_amdgcn_mfma_f32_16x16x32_bf16(a3, b0, acc[3][0], 0, 0, 0);
                acc[3][1] = __builtin_amdgcn_mfma_f32_16x16x32_bf16(a3, b1, acc[3][1], 0, 0, 0);
            }
        }
    }

    if (wv < 8) {
        #pragma unroll
        for (int m = 0; m < 4; ++m)
            #pragma unroll
            for (int n = 0; n < 2; ++n)
                #pragma unroll
                for (int r = 0; r < 4; ++r) {
                    int o  = mg + m * 16 + l16 * 4 + r;
                    int hw = hw0 + pg + n * 16 + l15;
                    long oi = xb + (long)o * HW_ + hw;
                    out[oi] = acc[m][n][r] + bias[o] + x[oi];
                }
    }
}

extern "C" void kernel_launch(void* const* d_in, const int* in_sizes, int n_in,
                              void* d_out, int out_size, void* d_ws, size_t ws_size,
                              hipStream_t stream) {
    const float* x      = (const float*)d_in[0];
    const float* prob   = (const float*)d_in[1];
    const float* table  = (const float*)d_in[2];
    const float* weight = (const float*)d_in[3];
    const float* bias   = (const float*)d_in[4];
    float* out = (float*)d_out;

    const size_t wp_bytes  = (size_t)CH_ * KTOT_ * 2;          // 1,179,648
    const size_t m_bytes   = (size_t)NPIX_ * 4;                // 122,880
    const size_t off_bytes = (size_t)NPIX_ * 18 * 4;           // 2,211,840
    const size_t xt_bytes  = (size_t)NPIX_ * CH_ * 2;          // 15,728,640
    const size_t col_bytes = (size_t)NBLK_ * NCHK_ * COLB_;    // 141,557,760

    ushort* wp_ws  = (ushort*)d_ws;
    float*  m_ws   = (float*)((char*)d_ws + wp_bytes);
    float*  off_ws = (float*)((char*)d_ws + wp_bytes + m_bytes);
    ushort* xt_ws  = (ushort*)((char*)d_ws + wp_bytes + m_bytes + off_bytes);
    ushort* col_ws = (ushort*)((char*)d_ws + wp_bytes + m_bytes + off_bytes + xt_bytes);

    const size_t need_v11 = wp_bytes + m_bytes + off_bytes + xt_bytes;
    const size_t need_v19 = need_v11 + col_bytes;

    if (ws_size >= need_v19) {
        prep_weight2<<<(CH_ * KTOT_ + 255) / 256, 256, 0, stream>>>(weight, wp_ws);
        prep_xt<<<(HW_ / 128) * 4 * B_, 256, 0, stream>>>(x, xt_ws);
        gating_kernel<<<NPIX_ / 256, 256, 0, stream>>>(prob, table, m_ws, off_ws);
        im2col_k4<<<NBLK_ * NCHK_, 576, 0, stream>>>(xt_ws, m_ws, off_ws, col_ws);
        conv_gemm6<<<NB5_, 576, 0, stream>>>(x, col_ws, wp_ws, bias, out);
    } else if (ws_size >= need_v11) {
        prep_weight2<<<(CH_ * KTOT_ + 255) / 256, 256, 0, stream>>>(weight, wp_ws);
        prep_xt<<<(HW_ / 128) * 4 * B_, 256, 0, stream>>>(x, xt_ws);
        conv_mfma11<<<NBLK_, 576, 0, stream>>>(x, xt_ws, wp_ws, prob, table, bias, out);
    } else {
        gating_kernel<<<NPIX_ / 256, 256, 0, stream>>>(prob, table, m_ws, off_ws);
        prep_weight<<<(CH_ * KTOT_ + 255) / 256, 256, 0, stream>>>(weight, wp_ws);
        conv_mfma2<<<NPIX_ / PT2_, 576, 0, stream>>>(x, wp_ws, bias, m_ws, off_ws, out);
    }
}

// Round 9
// 145.367 us; speedup vs baseline: 1.0818x; 1.0265x over previous
//
#include <hip/hip_runtime.h>
#include <math.h>

#define B_    4
#define CH_   256
#define H_    48
#define W_    160
#define A_    36
#define K2_   9
#define HW_   (H_*W_)        // 7680
#define NPIX_ (B_*HW_)       // 30720
#define KTOT_ (CH_*K2_)      // 2304
#define CPC_  32             // channels per chunk
#define KC_   (CPC_*K2_)     // 288 k' per chunk
#define NCHK_ (CH_/CPC_)     // 8
#define NKST_ (KTOT_/32)     // 72 k-steps of 32
#define LSTR_ 296            // LDS row stride (ushort) for v11/v2 paths
#define PT2_  64             // pixel tile (col image granularity)
#define NBLK_ (NPIX_/PT2_)   // 480 col pixel-blocks
#define COLB_ 36864          // bytes per (64px-block,chunk) col image: 36 gran*64px*16B
#define COLW_ (COLB_/2)      // 18432 ushorts
#define PT5_  128            // GEMM pixel tile
#define NB5_  (NPIX_/PT5_)   // 240 GEMM blocks
#define TSTR_ 520            // im2col LDS granule stride (ushorts) = 1040B (pad)

typedef __attribute__((ext_vector_type(8))) short bf16x8;
typedef __attribute__((ext_vector_type(4))) float f32x4;

__device__ inline ushort f2bf(float f) {
    union { float f; unsigned u; } c; c.f = f;
    unsigned r = c.u + 0x7FFFu + ((c.u >> 16) & 1u);
    return (ushort)(r >> 16);
}
__device__ inline float bf2f(ushort u) {
    union { unsigned u; float f; } c; c.u = (unsigned)u << 16; return c.f;
}

// async global->LDS, 16B per lane: LDS dest = wave-uniform base + lane*16
__device__ inline void gld_lds16(const ushort* g, ushort* l) {
    __builtin_amdgcn_global_load_lds(
        (const __attribute__((address_space(1))) unsigned int*)(g),
        (__attribute__((address_space(3))) unsigned int*)(l),
        16, 0, 0);
}

// ---------------- weight fp32 -> bf16, MFMA-fragment-ordered ----------------
__global__ __launch_bounds__(256)
void prep_weight2(const float* __restrict__ w, ushort* __restrict__ wp2) {
    int t = blockIdx.x * 256 + threadIdx.x;
    if (t >= CH_ * KTOT_) return;
    int j    = t & 7;
    int lane = (t >> 3) & 63;
    int kk   = t >> 9;             // 0..1151
    int kst  = kk % NKST_;
    int rg   = kk / NKST_;         // 0..15
    int row  = rg * 16 + (lane & 15);
    int kq   = kst * 32 + (lane >> 4) * 8 + j;   // k'
    int chunk = kq / KC_, r = kq % KC_;
    int tap = r / CPC_, ci = r % CPC_;
    int c = chunk * CPC_ + ci;
    wp2[t] = f2bf(w[(row * CH_ + c) * K2_ + tap]);
}

// ---------------- weight fp32 -> bf16, K-permuted (fallback layout) ----------
__global__ __launch_bounds__(256)
void prep_weight(const float* __restrict__ w, ushort* __restrict__ wp) {
    int t = blockIdx.x * 256 + threadIdx.x;
    if (t >= CH_ * KTOT_) return;
    int o  = t / KTOT_, kk = t % KTOT_;
    int chunk = kk / KC_, r = kk % KC_;
    int tap = r / CPC_, ci = r % CPC_;
    int c = chunk * CPC_ + ci;
    wp[t] = f2bf(w[(o * CH_ + c) * K2_ + tap]);
}

// ---------------- x [B,C,HW] f32 -> xt [B,HW,C] bf16 ----------------
__global__ __launch_bounds__(256)
void prep_xt(const float* __restrict__ x, ushort* __restrict__ xt) {
    int bid = blockIdx.x;
    int hwT = bid % (HW_ / 128);           // 60
    int rest = bid / (HW_ / 128);
    int cT = rest & 3;
    int b  = rest >> 2;
    int hw0 = hwT * 128, c0 = cT * 64;
    int tid = threadIdx.x;
    int u = tid & 7, s = tid >> 3;
    const float* xb = x + ((long)b * CH_ + c0 + u * 8) * HW_ + hw0 + s * 4;
    float4 L[8];
    #pragma unroll
    for (int i = 0; i < 8; ++i) L[i] = *(const float4*)(xb + (long)i * HW_);
    ushort* xo = xt + ((long)b * HW_ + hw0 + s * 4) * CH_ + c0 + u * 8;
    #pragma unroll
    for (int j = 0; j < 4; ++j) {
        bf16x8 o;
        #pragma unroll
        for (int i = 0; i < 8; ++i) {
            float f = (j == 0) ? L[i].x : (j == 1) ? L[i].y : (j == 2) ? L[i].z : L[i].w;
            o[i] = (short)f2bf(f);
        }
        *(bf16x8*)(xo + (long)j * CH_) = o;
    }
}

// ---------------- top-k gating + offset blend -> m, off (global) ----------
__global__ __launch_bounds__(256)
void gating_kernel(const float* __restrict__ prob,
                   const float* __restrict__ table,
                   float* __restrict__ m_out,
                   float* __restrict__ off_out) {
    int pix = blockIdx.x * 256 + threadIdx.x;
    if (pix >= NPIX_) return;
    int b  = pix / HW_;
    int hw = pix % HW_;
    const float* pr = prob + (long)b * A_ * HW_ + hw;

    float v0 = -1e30f, v1 = -1e30f, v2 = -1e30f;
    int   i0 = 0, i1 = 0, i2 = 0;
    #pragma unroll 4
    for (int a = 0; a < A_; ++a) {
        float v = pr[(long)a * HW_];
        if (v > v0)      { v2=v1; i2=i1; v1=v0; i1=i0; v0=v; i0=a; }
        else if (v > v1) { v2=v1; i2=i1; v1=v;  i1=a; }
        else if (v > v2) { v2=v;  i2=a; }
    }
    float e1 = expf(v1 - v0), e2 = expf(v2 - v0);
    float inv = 1.0f / (1.0f + e1 + e2);
    float s0 = inv, s1 = e1*inv, s2 = e2*inv;
    float hard = (v0 > 0.5f) ? 1.0f : 0.0f;

    m_out[pix] = v0;
    const float* t0 = table + ((long)i0 * 18) * HW_ + hw;
    const float* t1 = table + ((long)i1 * 18) * HW_ + hw;
    const float* t2 = table + ((long)i2 * 18) * HW_ + hw;
    float* op = off_out + (long)pix * 18;
    #pragma unroll
    for (int c = 0; c < 18; ++c) {
        float o = s0 * t0[(long)c * HW_] + s1 * t1[(long)c * HW_] + s2 * t2[(long)c * HW_];
        op[c] = o * hard;
    }
}

// ======== im2col_k4 (proven 54us, round-6 verbatim): coalesced both ends ====
__global__ __launch_bounds__(576)
void im2col_k4(const ushort* __restrict__ xt,
               const float* __restrict__ m_arr,
               const float* __restrict__ off_arr,
               ushort* __restrict__ colg) {
    __shared__ __align__(16) ushort tb[36 * TSTR_];   // 37440 B

    const int tid  = threadIdx.x;
    const int lane = tid & 63;
    const int wv   = tid >> 6;            // 0..8
    const int bid  = (int)blockIdx.x;
    const int chI  = bid & 7;             // chunk == XCD slot
    const int pbk  = bid >> 3;            // 0..479 pixel-block
    const int pb   = pbk * PT2_;
    const int b    = pb / HW_;
    const int hw0  = pb % HW_;
    const ushort* xtb = xt + (long)b * HW_ * CH_;
    ushort* cgo = colg + (long)pbk * (NCHK_ * COLW_) + (long)chI * COLW_;

    const int sseg = lane & 3;
    const int qd   = lane >> 2;
    const int cb0  = chI * CPC_ + sseg * 8;

    int   coff[4][4];
    float cwgt[4][4];
    int   ldst[4];
    #pragma unroll
    for (int g = 0; g < 4; ++g) {
        int pr = g * 144 + wv * 16 + qd;   // bijective over 0..575
        int px = pr & 63, kt = pr >> 6;
        int hw = hw0 + px;
        int pix = pb + px;
        int h  = hw / W_, w_ = hw % W_;
        float m    = m_arr[pix];
        float2 ohw = *(const float2*)(off_arr + (long)pix * 18 + 2 * kt);
        float py  = (float)(h  + (kt / 3 - 1)) + ohw.x;
        float pxf = (float)(w_ + (kt % 3 - 1)) + ohw.y;
        float y0f = floorf(py), x0f = floorf(pxf);
        float dy = py - y0f,   dx = pxf - x0f;
        int y0 = (int)y0f, x0i = (int)x0f;
        int y1 = y0 + 1,   x1  = x0i + 1;
        float vy0 = (y0  >= 0 && y0  < H_) ? 1.f : 0.f;
        float vy1 = (y1  >= 0 && y1  < H_) ? 1.f : 0.f;
        float vx0 = (x0i >= 0 && x0i < W_) ? 1.f : 0.f;
        float vx1 = (x1  >= 0 && x1  < W_) ? 1.f : 0.f;
        int cy0 = min(max(y0, 0),  H_-1), cy1 = min(max(y1, 0), H_-1);
        int cx0 = min(max(x0i, 0), W_-1), cx1 = min(max(x1, 0), W_-1);
        coff[g][0] = (cy0*W_ + cx0) * CH_ + cb0;  cwgt[g][0] = (1.f-dy)*(1.f-dx)*vy0*vx0*m;
        coff[g][1] = (cy0*W_ + cx1) * CH_ + cb0;  cwgt[g][1] = (1.f-dy)*dx      *vy0*vx1*m;
        coff[g][2] = (cy1*W_ + cx0) * CH_ + cb0;  cwgt[g][2] = dy      *(1.f-dx)*vy1*vx0*m;
        coff[g][3] = (cy1*W_ + cx1) * CH_ + cb0;  cwgt[g][3] = dy      *dx      *vy1*vx1*m;
        ldst[g] = (kt * 4 + sseg) * TSTR_ + px * 8;   // transpose-buffer slot
    }

    // phase 1: 16 coalesced gathers -> blend -> 4 LDS writes
    bf16x8 d[4][4];
    #pragma unroll
    for (int g = 0; g < 4; ++g)
        #pragma unroll
        for (int c = 0; c < 4; ++c)
            d[g][c] = *(const bf16x8*)(xtb + coff[g][c]);
    #pragma unroll
    for (int g = 0; g < 4; ++g) {
        float a8[8];
        #pragma unroll
        for (int j = 0; j < 8; ++j) a8[j] = 0.f;
        #pragma unroll
        for (int c = 0; c < 4; ++c) {
            float wgt = cwgt[g][c];
            #pragma unroll
            for (int j = 0; j < 8; ++j)
                a8[j] = fmaf(wgt, bf2f((ushort)d[g][c][j]), a8[j]);
        }
        bf16x8 o;
        #pragma unroll
        for (int j = 0; j < 8; ++j) o[j] = (short)f2bf(a8[j]);
        *(bf16x8*)(&tb[ldst[g]]) = o;
    }
    __syncthreads();

    // phase 2: granule-major re-read (linear b128) -> 1KB-contiguous stores
    #pragma unroll
    for (int g = 0; g < 4; ++g) {
        const int G = g * 9 + wv;          // 0..35
        bf16x8 o = *(const bf16x8*)(&tb[G * TSTR_ + lane * 8]);
        *(bf16x8*)(cgo + (G * 64 + lane) * 8) = o;
    }
}

// ======== v20: PT=128 GEMM with DRIBBLED staging ========
// gemm5's burst problem: all 16 staging gld_lds issued up front, then the
// first weight-consumption vmcnt (weights are NEWER in the FIFO) forces all
// 16 complete early in compute -> memory idles the rest of the iteration.
// Fix: issue 2 staging parts per ks step, AFTER that step's weight loads in
// program order. The compiler's automatic vmcnt counting then leaves parts
// issued at step ks in flight until much later weight waits -> memory pipe
// continuously fed across the iteration with zero extra registers and no
// sched_barrier. __syncthreads at iter end drains only the (mostly
// complete) tail parts. Compute body identical to gemm5 (proven <53us).
__global__ __launch_bounds__(576, 1)
void conv_gemm7(const float* __restrict__ x,
                const ushort* __restrict__ colg,
                const ushort* __restrict__ wp2,
                const float* __restrict__ bias,
                float* __restrict__ out) {
    __shared__ __align__(16) ushort colL[4 * COLW_];   // 147456 B

    const int tid  = threadIdx.x;
    const int lane = tid & 63;
    const int wv   = tid >> 6;            // 0..8
    const int l15  = lane & 15;
    const int l16  = lane >> 4;
    const int bid  = (int)blockIdx.x;     // 0..239
    const int pb   = bid * PT5_;
    const int b    = pb / HW_;
    const int hw0  = pb % HW_;
    const long xb  = (long)b * CH_ * HW_;
    const long pbk64 = (long)bid * 2;     // two 64px col blocks

    f32x4 acc[2][8];
    #pragma unroll
    for (int m = 0; m < 2; ++m)
        #pragma unroll
        for (int n = 0; n < 8; ++n)
            acc[m][n] = (f32x4)(0.f);

    const int rg0 = wv * 2;
    const int mg  = wv * 32;

    // one 16B gld_lds per thread per part; parts 0..7 cover (hf 0..1, i 0..3)
    auto STAGEPART = [&](int chI, int bufi, int part) {
        const int hf = part >> 2, i = part & 3;
        const ushort* src = colg + ((pbk64 + hf) * NCHK_ + chI) * COLW_;
        ushort* dst = colL + (bufi * 2 + hf) * COLW_;
        const int go = (wv * 4 + i) * 512;
        gld_lds16(src + go + lane * 8, dst + go);
    };

    // prologue: fully stage chunk 0
    #pragma unroll
    for (int p = 0; p < 8; ++p) STAGEPART(0, 0, p);
    __syncthreads();                       // buf0 ready

    for (int chI = 0; chI < NCHK_; ++chI) {
        const int cur = chI & 1, nxt = cur ^ 1;
        const bool pf = (chI < NCHK_ - 1);
        const ushort* wbase = wp2 + (((long)rg0 * NKST_ + chI * K2_) << 9) + (lane << 3);
        const long rstep = (long)NKST_ << 9;
        bf16x8 a0, a1;
        if (wv < 8) {
            a0 = *(const bf16x8*)(wbase);
            a1 = *(const bf16x8*)(wbase + rstep);
        }
        #pragma unroll
        for (int ks = 0; ks < K2_; ++ks) {
            if (pf && ks < 8) STAGEPART(chI + 1, nxt, ks);   // dribble: 1/ks
            if (wv < 8) {
                bf16x8 a0n, a1n;
                if (ks < K2_ - 1) {                     // prefetch next ks
                    a0n = *(const bf16x8*)(wbase + ((ks + 1) << 9));
                    a1n = *(const bf16x8*)(wbase + rstep + ((ks + 1) << 9));
                }
                const ushort* cb0 = &colL[(cur * 2) * COLW_ + ((ks * 4 + l16) * 64 + l15) * 8];
                const ushort* cb1 = cb0 + COLW_;
                bf16x8 b0 = *(const bf16x8*)(cb0);
                bf16x8 b1 = *(const bf16x8*)(cb0 + 128);
                bf16x8 b2 = *(const bf16x8*)(cb0 + 256);
                bf16x8 b3 = *(const bf16x8*)(cb0 + 384);
                bf16x8 b4 = *(const bf16x8*)(cb1);
                bf16x8 b5 = *(const bf16x8*)(cb1 + 128);
                bf16x8 b6 = *(const bf16x8*)(cb1 + 256);
                bf16x8 b7 = *(const bf16x8*)(cb1 + 384);
                __builtin_amdgcn_s_setprio(1);
                acc[0][0] = __builtin_amdgcn_mfma_f32_16x16x32_bf16(a0, b0, acc[0][0], 0, 0, 0);
                acc[0][1] = __builtin_amdgcn_mfma_f32_16x16x32_bf16(a0, b1, acc[0][1], 0, 0, 0);
                acc[0][2] = __builtin_amdgcn_mfma_f32_16x16x32_bf16(a0, b2, acc[0][2], 0, 0, 0);
                acc[0][3] = __builtin_amdgcn_mfma_f32_16x16x32_bf16(a0, b3, acc[0][3], 0, 0, 0);
                acc[0][4] = __builtin_amdgcn_mfma_f32_16x16x32_bf16(a0, b4, acc[0][4], 0, 0, 0);
                acc[0][5] = __builtin_amdgcn_mfma_f32_16x16x32_bf16(a0, b5, acc[0][5], 0, 0, 0);
                acc[0][6] = __builtin_amdgcn_mfma_f32_16x16x32_bf16(a0, b6, acc[0][6], 0, 0, 0);
                acc[0][7] = __builtin_amdgcn_mfma_f32_16x16x32_bf16(a0, b7, acc[0][7], 0, 0, 0);
                acc[1][0] = __builtin_amdgcn_mfma_f32_16x16x32_bf16(a1, b0, acc[1][0], 0, 0, 0);
                acc[1][1] = __builtin_amdgcn_mfma_f32_16x16x32_bf16(a1, b1, acc[1][1], 0, 0, 0);
                acc[1][2] = __builtin_amdgcn_mfma_f32_16x16x32_bf16(a1, b2, acc[1][2], 0, 0, 0);
                acc[1][3] = __builtin_amdgcn_mfma_f32_16x16x32_bf16(a1, b3, acc[1][3], 0, 0, 0);
                acc[1][4] = __builtin_amdgcn_mfma_f32_16x16x32_bf16(a1, b4, acc[1][4], 0, 0, 0);
                acc[1][5] = __builtin_amdgcn_mfma_f32_16x16x32_bf16(a1, b5, acc[1][5], 0, 0, 0);
                acc[1][6] = __builtin_amdgcn_mfma_f32_16x16x32_bf16(a1, b6, acc[1][6], 0, 0, 0);
                acc[1][7] = __builtin_amdgcn_mfma_f32_16x16x32_bf16(a1, b7, acc[1][7], 0, 0, 0);
                __builtin_amdgcn_s_setprio(0);
                if (ks < K2_ - 1) { a0 = a0n; a1 = a1n; }
            }
        }
        __syncthreads();                   // tail parts drain (mostly done)
    }

    if (wv < 8) {
        #pragma unroll
        for (int m = 0; m < 2; ++m)
            #pragma unroll
            for (int n = 0; n < 8; ++n)
                #pragma unroll
                for (int r = 0; r < 4; ++r) {
                    int o  = mg + m * 16 + l16 * 4 + r;
                    int hw = hw0 + n * 16 + l15;
                    long oi = xb + (long)o * HW_ + hw;
                    out[oi] = acc[m][n][r] + bias[o] + x[oi];
                }
    }
}

// ======== v11 (proven 140 us) — mid-tier if ws can't hold col ========
__global__ __launch_bounds__(576)
void conv_mfma11(const float* __restrict__ x,
                 const ushort* __restrict__ xt,
                 const ushort* __restrict__ wp2,
                 const float* __restrict__ prob,
                 const float* __restrict__ table,
                 const float* __restrict__ bias,
                 float* __restrict__ out) {
    __shared__ __align__(16) ushort col[2][PT2_ * LSTR_];   // 75776 B
    __shared__ float off_l[PT2_ * 18];
    __shared__ float m_l[PT2_];

    const int tid  = threadIdx.x;
    const int lane = tid & 63;
    const int wv   = tid >> 6;
    const int l15  = lane & 15;
    const int l16  = lane >> 4;
    const int bid  = (int)blockIdx.x;
    const int bswz = (bid & 7) * (NBLK_ / 8) + (bid >> 3);
    const int pb   = bswz * PT2_;
    const int b    = pb / HW_;
    const int hw0  = pb % HW_;
    const long xb  = (long)b * CH_ * HW_;
    const ushort* xtb = xt + (long)b * HW_ * CH_;

    if (tid < PT2_) {
        const int px = tid;
        const int hw = hw0 + px;
        const float* pr = prob + (long)b * A_ * HW_ + hw;
        float v0 = -1e30f, v1 = -1e30f, v2 = -1e30f;
        int   i0 = 0, i1 = 0, i2 = 0;
        #pragma unroll 4
        for (int a = 0; a < A_; ++a) {
            float v = pr[(long)a * HW_];
            if (v > v0)      { v2=v1; i2=i1; v1=v0; i1=i0; v0=v; i0=a; }
            else if (v > v1) { v2=v1; i2=i1; v1=v;  i1=a; }
            else if (v > v2) { v2=v;  i2=a; }
        }
        float e1 = expf(v1 - v0), e2 = expf(v2 - v0);
        float inv = 1.0f / (1.0f + e1 + e2);
        float s0 = inv, s1 = e1*inv, s2 = e2*inv;
        float hard = (v0 > 0.5f) ? 1.0f : 0.0f;
        m_l[px] = v0;
        const float* t0 = table + ((long)i0 * 18) * HW_ + hw;
        const float* t1 = table + ((long)i1 * 18) * HW_ + hw;
        const float* t2 = table + ((long)i2 * 18) * HW_ + hw;
        #pragma unroll
        for (int c = 0; c < 18; ++c) {
            float o = s0 * t0[(long)c * HW_] + s1 * t1[(long)c * HW_] + s2 * t2[(long)c * HW_];
            off_l[px * 18 + c] = o * hard;
        }
    }
    __syncthreads();

    const int sseg = lane & 3;
    const int qd   = lane >> 2;
    int   coff[4][4];
    float cwgt[4][4];
    int   dsto[4];
    #pragma unroll
    for (int g = 0; g < 4; ++g) {
        int pr = g * 144 + wv * 16 + qd;
        int px = pr & 63, kt = pr >> 6;
        int hw = hw0 + px;
        int h  = hw / W_, w_ = hw % W_;
        float m    = m_l[px];
        float offh = off_l[px * 18 + 2*kt];
        float offw = off_l[px * 18 + 2*kt + 1];
        float py  = (float)(h  + (kt / 3 - 1)) + offh;
        float pxf = (float)(w_ + (kt % 3 - 1)) + offw;
        float y0f = floorf(py), x0f = floorf(pxf);
        float dy = py - y0f,   dx = pxf - x0f;
        int y0 = (int)y0f, x0i = (int)x0f;
        int y1 = y0 + 1,   x1  = x0i + 1;
        float vy0 = (y0  >= 0 && y0  < H_) ? 1.f : 0.f;
        float vy1 = (y1  >= 0 && y1  < H_) ? 1.f : 0.f;
        float vx0 = (x0i >= 0 && x0i < W_) ? 1.f : 0.f;
        float vx1 = (x1  >= 0 && x1  < W_) ? 1.f : 0.f;
        int cy0 = min(max(y0, 0),  H_-1), cy1 = min(max(y1, 0), H_-1);
        int cx0 = min(max(x0i, 0), W_-1), cx1 = min(max(x1, 0), W_-1);
        coff[g][0] = (cy0*W_ + cx0) * CH_;  cwgt[g][0] = (1.f-dy)*(1.f-dx)*vy0*vx0*m;
        coff[g][1] = (cy0*W_ + cx1) * CH_;  cwgt[g][1] = (1.f-dy)*dx      *vy0*vx1*m;
        coff[g][2] = (cy1*W_ + cx0) * CH_;  cwgt[g][2] = dy      *(1.f-dx)*vy1*vx0*m;
        coff[g][3] = (cy1*W_ + cx1) * CH_;  cwgt[g][3] = dy      *dx      *vy1*vx1*m;
        dsto[g] = px * LSTR_ + kt * CPC_ + sseg * 8;
    }

    f32x4 acc[2][4];
    #pragma unroll
    for (int m = 0; m < 2; ++m)
        #pragma unroll
        for (int n = 0; n < 4; ++n)
            acc[m][n] = (f32x4)(0.f);

    const int rg0 = wv * 2;
    const int mg  = wv * 32;

    bf16x8 d[2][4];

    auto LOADpair = [&](int chI, int g0) {
        const int cb0 = chI * CPC_ + sseg * 8;
        #pragma unroll
        for (int gg = 0; gg < 2; ++gg)
            #pragma unroll
            for (int c = 0; c < 4; ++c)
                d[gg][c] = *(const bf16x8*)(xtb + coff[g0 + gg][c] + cb0);
    };
    auto WRITEpair = [&](int bufi, int g0) {
        #pragma unroll
        for (int gg = 0; gg < 2; ++gg) {
            float a8[8];
            #pragma unroll
            for (int j = 0; j < 8; ++j) a8[j] = 0.f;
            #pragma unroll
            for (int c = 0; c < 4; ++c) {
                float wgt = cwgt[g0 + gg][c];
                #pragma unroll
                for (int j = 0; j < 8; ++j)
                    a8[j] = fmaf(wgt, bf2f((ushort)d[gg][c][j]), a8[j]);
            }
            bf16x8 o;
            #pragma unroll
            for (int j = 0; j < 8; ++j) o[j] = (short)f2bf(a8[j]);
            *(bf16x8*)(&col[bufi][dsto[g0 + gg]]) = o;
        }
    };
    auto COMPUTEhalf = [&](int bufi, int chI, int ks0, int ks1) {
        if (wv < 8) {
            for (int ks = ks0; ks < ks1; ++ks) {
                const int kst = chI * K2_ + ks;
                const ushort* wr = wp2 + (((long)rg0 * NKST_ + kst) << 9) + (lane << 3);
                bf16x8 a0 = *(const bf16x8*)(wr);
                bf16x8 a1 = *(const bf16x8*)(wr + (1l * NKST_ << 9));
                const ushort* cb = &col[bufi][l15 * LSTR_ + ks * 32 + 8 * l16];
                bf16x8 b0 = *(const bf16x8*)(cb);
                bf16x8 b1 = *(const bf16x8*)(cb + 16 * LSTR_);
                bf16x8 b2 = *(const bf16x8*)(cb + 32 * LSTR_);
                bf16x8 b3 = *(const bf16x8*)(cb + 48 * LSTR_);
                __builtin_amdgcn_s_setprio(1);
                acc[0][0] = __builtin_amdgcn_mfma_f32_16x16x32_bf16(a0, b0, acc[0][0], 0, 0, 0);
                acc[0][1] = __builtin_amdgcn_mfma_f32_16x16x32_bf16(a0, b1, acc[0][1], 0, 0, 0);
                acc[0][2] = __builtin_amdgcn_mfma_f32_16x16x32_bf16(a0, b2, acc[0][2], 0, 0, 0);
                acc[0][3] = __builtin_amdgcn_mfma_f32_16x16x32_bf16(a0, b3, acc[0][3], 0, 0, 0);
                acc[1][0] = __builtin_amdgcn_mfma_f32_16x16x32_bf16(a1, b0, acc[1][0], 0, 0, 0);
                acc[1][1] = __builtin_amdgcn_mfma_f32_16x16x32_bf16(a1, b1, acc[1][1], 0, 0, 0);
                acc[1][2] = __builtin_amdgcn_mfma_f32_16x16x32_bf16(a1, b2, acc[1][2], 0, 0, 0);
                acc[1][3] = __builtin_amdgcn_mfma_f32_16x16x32_bf16(a1, b3, acc[1][3], 0, 0, 0);
                __builtin_amdgcn_s_setprio(0);
            }
        }
    };

    LOADpair(0, 0); WRITEpair(0, 0);
    LOADpair(0, 2); WRITEpair(0, 2);
    __syncthreads();

    for (int chI = 0; chI < NCHK_; ++chI) {
        const int cur = chI & 1, nxt = cur ^ 1;
        const bool pf = (chI < NCHK_ - 1);
        if (pf) LOADpair(chI + 1, 0);
        COMPUTEhalf(cur, chI, 0, 4);
        if (pf) { WRITEpair(nxt, 0); LOADpair(chI + 1, 2); }
        COMPUTEhalf(cur, chI, 4, 9);
        if (pf) WRITEpair(nxt, 2);
        __syncthreads();
    }

    if (wv < 8) {
        #pragma unroll
        for (int m = 0; m < 2; ++m)
            #pragma unroll
            for (int n = 0; n < 4; ++n)
                #pragma unroll
                for (int r = 0; r < 4; ++r) {
                    int o  = mg + m * 16 + l16 * 4 + r;
                    int hw = hw0 + n * 16 + l15;
                    long oi = xb + (long)o * HW_ + hw;
                    out[oi] = acc[m][n][r] + bias[o] + x[oi];
                }
    }
}

// ======== v2 fallback (used if ws too small) ========
__global__ __launch_bounds__(576)
void conv_mfma2(const float* __restrict__ x,
                const ushort* __restrict__ wp,
                const float* __restrict__ bias,
                const float* __restrict__ m_arr,
                const float* __restrict__ off_arr,
                float* __restrict__ out) {
    __shared__ __align__(16) ushort col[PT2_ * LSTR_];

    const int tid  = threadIdx.x;
    const int lane = tid & 63;
    const int wv   = tid >> 6;
    const int l15  = lane & 15;
    const int l16  = lane >> 4;
    const int pb   = blockIdx.x * PT2_;
    const int b    = pb / HW_;
    const int hw0  = pb % HW_;
    const long xb  = (long)b * CH_ * HW_;

    int   id0, id1, id2, id3;
    float wg0, wg1, wg2, wg3;
    {
        int px = lane, kt = wv;
        int hw = hw0 + px;
        int h  = hw / W_, w_ = hw % W_;
        int pix = b * HW_ + hw;
        float m    = m_arr[pix];
        float offh = off_arr[(long)pix * 18 + 2*kt];
        float offw = off_arr[(long)pix * 18 + 2*kt + 1];
        float py = (float)(h  + (kt / 3 - 1)) + offh;
        float px_= (float)(w_ + (kt % 3 - 1)) + offw;
        float y0f = floorf(py), x0f = floorf(px_);
        float dy = py - y0f,   dx = px_ - x0f;
        int y0 = (int)y0f, x0 = (int)x0f;
        int y1 = y0 + 1,   x1 = x0 + 1;
        float vy0 = (y0 >= 0 && y0 < H_) ? 1.f : 0.f;
        float vy1 = (y1 >= 0 && y1 < H_) ? 1.f : 0.f;
        float vx0 = (x0 >= 0 && x0 < W_) ? 1.f : 0.f;
        float vx1 = (x1 >= 0 && x1 < W_) ? 1.f : 0.f;
        int cy0 = min(max(y0, 0), H_-1), cy1 = min(max(y1, 0), H_-1);
        int cx0 = min(max(x0, 0), W_-1), cx1 = min(max(x1, 0), W_-1);
        id0 = cy0*W_ + cx0;  wg0 = (1.f-dy)*(1.f-dx)*vy0*vx0*m;
        id1 = cy0*W_ + cx1;  wg1 = (1.f-dy)*dx      *vy0*vx1*m;
        id2 = cy1*W_ + cx0;  wg2 = dy      *(1.f-dx)*vy1*vx0*m;
        id3 = cy1*W_ + cx1;  wg3 = dy      *dx      *vy1*vx1*m;
    }

    f32x4 acc[4][2];
    #pragma unroll
    for (int m = 0; m < 4; ++m)
        #pragma unroll
        for (int n = 0; n < 2; ++n)
            acc[m][n] = (f32x4)(0.f);

    const int mg = (wv & 3) * 64;
    const int pg = (wv >> 2) * 32;

    for (int chI = 0; chI < NCHK_; ++chI) {
        __syncthreads();
        {
            const int c0 = chI * CPC_;
            ushort* dst = &col[lane * LSTR_ + wv * CPC_];
            #pragma unroll
            for (int c8 = 0; c8 < 4; ++c8) {
                bf16x8 pk;
                #pragma unroll
                for (int j = 0; j < 8; ++j) {
                    const float* xs = x + xb + (long)(c0 + c8*8 + j) * HW_;
                    float v = wg0 * xs[id0] + wg1 * xs[id1]
                            + wg2 * xs[id2] + wg3 * xs[id3];
                    pk[j] = (short)f2bf(v);
                }
                *(bf16x8*)(dst + c8 * 8) = pk;
            }
        }
        __syncthreads();
        if (wv < 8) {
            #pragma unroll
            for (int ks = 0; ks < K2_; ++ks) {
                const int kg = chI * KC_ + ks * 32 + 8 * l16;
                const ushort* wr = wp + (long)(mg + l15) * KTOT_ + kg;
                bf16x8 a0 = *(const bf16x8*)(wr);
                bf16x8 a1 = *(const bf16x8*)(wr + 16 * KTOT_);
                bf16x8 a2 = *(const bf16x8*)(wr + 32 * KTOT_);
                bf16x8 a3 = *(const bf16x8*)(wr + 48 * KTOT_);
                const ushort* cb = &col[(pg + l15) * LSTR_ + ks * 32 + 8 * l16];
                bf16x8 b0 = *(const bf16x8*)(cb);
                bf16x8 b1 = *(const bf16x8*)(cb + 16 * LSTR_);
                acc[0][0] = __builtin_amdgcn_mfma_f32_16x16x32_bf16(a0, b0, acc[0][0], 0, 0, 0);
                acc[0][1] = __builtin_amdgcn_mfma_f32_16x16x32_bf16(a0, b1, acc[0][1], 0, 0, 0);
                acc[1][0] = __builtin_amdgcn_mfma_f32_16x16x32_bf16(a1, b0, acc[1][0], 0, 0, 0);
                acc[1][1] = __builtin_amdgcn_mfma_f32_16x16x32_bf16(a1, b1, acc[1][1], 0, 0, 0);
                acc[2][0] = __builtin_amdgcn_mfma_f32_16x16x32_bf16(a2, b0, acc[2][0], 0, 0, 0);
                acc[2][1] = __builtin_amdgcn_mfma_f32_16x16x32_bf16(a2, b1, acc[2][1], 0, 0, 0);
                acc[3][0] = __builtin_amdgcn_mfma_f32_16x16x32_bf16(a3, b0, acc[3][0], 0, 0, 0);
                acc[3][1] = __builtin_amdgcn_mfma_f32_16x16x32_bf16(a3, b1, acc[3][1], 0, 0, 0);
            }
        }
    }

    if (wv < 8) {
        #pragma unroll
        for (int m = 0; m < 4; ++m)
            #pragma unroll
            for (int n = 0; n < 2; ++n)
                #pragma unroll
                for (int r = 0; r < 4; ++r) {
                    int o  = mg + m * 16 + l16 * 4 + r;
                    int hw = hw0 + pg + n * 16 + l15;
                    long oi = xb + (long)o * HW_ + hw;
                    out[oi] = acc[m][n][r] + bias[o] + x[oi];
                }
    }
}

extern "C" void kernel_launch(void* const* d_in, const int* in_sizes, int n_in,
                              void* d_out, int out_size, void* d_ws, size_t ws_size,
                              hipStream_t stream) {
    const float* x      = (const float*)d_in[0];
    const float* prob   = (const float*)d_in[1];
    const float* table  = (const float*)d_in[2];
    const float* weight = (const float*)d_in[3];
    const float* bias   = (const float*)d_in[4];
    float* out = (float*)d_out;

    const size_t wp_bytes  = (size_t)CH_ * KTOT_ * 2;          // 1,179,648
    const size_t m_bytes   = (size_t)NPIX_ * 4;                // 122,880
    const size_t off_bytes = (size_t)NPIX_ * 18 * 4;           // 2,211,840
    const size_t xt_bytes  = (size_t)NPIX_ * CH_ * 2;          // 15,728,640
    const size_t col_bytes = (size_t)NBLK_ * NCHK_ * COLB_;    // 141,557,760

    ushort* wp_ws  = (ushort*)d_ws;
    float*  m_ws   = (float*)((char*)d_ws + wp_bytes);
    float*  off_ws = (float*)((char*)d_ws + wp_bytes + m_bytes);
    ushort* xt_ws  = (ushort*)((char*)d_ws + wp_bytes + m_bytes + off_bytes);
    ushort* col_ws = (ushort*)((char*)d_ws + wp_bytes + m_bytes + off_bytes + xt_bytes);

    const size_t need_v11 = wp_bytes + m_bytes + off_bytes + xt_bytes;
    const size_t need_v20 = need_v11 + col_bytes;

    if (ws_size >= need_v20) {
        prep_weight2<<<(CH_ * KTOT_ + 255) / 256, 256, 0, stream>>>(weight, wp_ws);
        prep_xt<<<(HW_ / 128) * 4 * B_, 256, 0, stream>>>(x, xt_ws);
        gating_kernel<<<NPIX_ / 256, 256, 0, stream>>>(prob, table, m_ws, off_ws);
        im2col_k4<<<NBLK_ * NCHK_, 576, 0, stream>>>(xt_ws, m_ws, off_ws, col_ws);
        conv_gemm7<<<NB5_, 576, 0, stream>>>(x, col_ws, wp_ws, bias, out);
    } else if (ws_size >= need_v11) {
        prep_weight2<<<(CH_ * KTOT_ + 255) / 256, 256, 0, stream>>>(weight, wp_ws);
        prep_xt<<<(HW_ / 128) * 4 * B_, 256, 0, stream>>>(x, xt_ws);
        conv_mfma11<<<NBLK_, 576, 0, stream>>>(x, xt_ws, wp_ws, prob, table, bias, out);
    } else {
        gating_kernel<<<NPIX_ / 256, 256, 0, stream>>>(prob, table, m_ws, off_ws);
        prep_weight<<<(CH_ * KTOT_ + 255) / 256, 256, 0, stream>>>(weight, wp_ws);
        conv_mfma2<<<NPIX_ / PT2_, 576, 0, stream>>>(x, wp_ws, bias, m_ws, off_ws, out);
    }
}

// Round 10
// 133.546 us; speedup vs baseline: 1.1776x; 1.0885x over previous
//
#include <hip/hip_runtime.h>
#include <math.h>

#define B_    4
#define CH_   256
#define H_    48
#define W_    160
#define A_    36
#define K2_   9
#define HW_   (H_*W_)        // 7680
#define NPIX_ (B_*HW_)       // 30720
#define KTOT_ (CH_*K2_)      // 2304
#define CPC_  32             // channels per chunk
#define KC_   (CPC_*K2_)     // 288 k' per chunk
#define NCHK_ (CH_/CPC_)     // 8
#define NKST_ (KTOT_/32)     // 72 k-steps of 32
#define LSTR_ 296            // LDS row stride (ushort) for v11/v2 paths
#define PT2_  64             // pixel tile (col image granularity)
#define NBLK_ (NPIX_/PT2_)   // 480 col pixel-blocks
#define COLB_ 36864          // bytes per (64px-block,chunk) col image: 36 gran*64px*16B
#define COLW_ (COLB_/2)      // 18432 ushorts
#define PT5_  128            // GEMM pixel tile
#define NB5_  (NPIX_/PT5_)   // 240 GEMM blocks
#define TSTR_ 520            // im2col LDS granule stride (ushorts) = 1040B (pad)

// fused-prep grid sections
#define NB_XT_  960          // prep_xt blocks
#define NB_GT_  120          // gating blocks
#define NB_W2_  2304         // prep_weight2 blocks
#define NB_ALL_ (NB_XT_ + NB_GT_ + NB_W2_)   // 3384

typedef __attribute__((ext_vector_type(8))) short bf16x8;
typedef __attribute__((ext_vector_type(4))) float f32x4;

__device__ inline ushort f2bf(float f) {
    union { float f; unsigned u; } c; c.f = f;
    unsigned r = c.u + 0x7FFFu + ((c.u >> 16) & 1u);
    return (ushort)(r >> 16);
}
__device__ inline float bf2f(ushort u) {
    union { unsigned u; float f; } c; c.u = (unsigned)u << 16; return c.f;
}

// async global->LDS, 16B per lane: LDS dest = wave-uniform base + lane*16
__device__ inline void gld_lds16(const ushort* g, ushort* l) {
    __builtin_amdgcn_global_load_lds(
        (const __attribute__((address_space(1))) unsigned int*)(g),
        (__attribute__((address_space(3))) unsigned int*)(l),
        16, 0, 0);
}

// ======== fused prep: prep_xt [0,960) | gating [960,1080) | weight [1080,3384)
// Three independent streaming preps in ONE launch: kills 2 launch gaps and
// the per-kernel tail under-subscription (they sum ~110MB, BW floor ~17us,
// were costing ~29us as 3 serial launches). Roles are block-uniform.
__global__ __launch_bounds__(256)
void prep_all(const float* __restrict__ x,  ushort* __restrict__ xt,
              const float* __restrict__ prob, const float* __restrict__ table,
              float* __restrict__ m_out, float* __restrict__ off_out,
              const float* __restrict__ w,  ushort* __restrict__ wp2) {
    const int bid = blockIdx.x;
    const int tid = threadIdx.x;

    if (bid < NB_XT_) {
        // ---- prep_xt: x [B,C,HW] f32 -> xt [B,HW,C] bf16 ----
        int hwT = bid % (HW_ / 128);           // 60
        int rest = bid / (HW_ / 128);
        int cT = rest & 3;
        int b  = rest >> 2;
        int hw0 = hwT * 128, c0 = cT * 64;
        int u = tid & 7, s = tid >> 3;
        const float* xb = x + ((long)b * CH_ + c0 + u * 8) * HW_ + hw0 + s * 4;
        float4 L[8];
        #pragma unroll
        for (int i = 0; i < 8; ++i) L[i] = *(const float4*)(xb + (long)i * HW_);
        ushort* xo = xt + ((long)b * HW_ + hw0 + s * 4) * CH_ + c0 + u * 8;
        #pragma unroll
        for (int j = 0; j < 4; ++j) {
            bf16x8 o;
            #pragma unroll
            for (int i = 0; i < 8; ++i) {
                float f = (j == 0) ? L[i].x : (j == 1) ? L[i].y : (j == 2) ? L[i].z : L[i].w;
                o[i] = (short)f2bf(f);
            }
            *(bf16x8*)(xo + (long)j * CH_) = o;
        }
    } else if (bid < NB_XT_ + NB_GT_) {
        // ---- gating: top-3 + softmax + thresh -> m, off ----
        int pix = (bid - NB_XT_) * 256 + tid;
        if (pix >= NPIX_) return;
        int b  = pix / HW_;
        int hw = pix % HW_;
        const float* pr = prob + (long)b * A_ * HW_ + hw;

        float v0 = -1e30f, v1 = -1e30f, v2 = -1e30f;
        int   i0 = 0, i1 = 0, i2 = 0;
        #pragma unroll 4
        for (int a = 0; a < A_; ++a) {
            float v = pr[(long)a * HW_];
            if (v > v0)      { v2=v1; i2=i1; v1=v0; i1=i0; v0=v; i0=a; }
            else if (v > v1) { v2=v1; i2=i1; v1=v;  i1=a; }
            else if (v > v2) { v2=v;  i2=a; }
        }
        float e1 = expf(v1 - v0), e2 = expf(v2 - v0);
        float inv = 1.0f / (1.0f + e1 + e2);
        float s0 = inv, s1 = e1*inv, s2 = e2*inv;
        float hard = (v0 > 0.5f) ? 1.0f : 0.0f;

        m_out[pix] = v0;
        const float* t0 = table + ((long)i0 * 18) * HW_ + hw;
        const float* t1 = table + ((long)i1 * 18) * HW_ + hw;
        const float* t2 = table + ((long)i2 * 18) * HW_ + hw;
        float* op = off_out + (long)pix * 18;
        #pragma unroll
        for (int c = 0; c < 18; ++c) {
            float o = s0 * t0[(long)c * HW_] + s1 * t1[(long)c * HW_] + s2 * t2[(long)c * HW_];
            op[c] = o * hard;
        }
    } else {
        // ---- prep_weight2: fp32 -> bf16, MFMA-fragment-ordered ----
        int t = (bid - NB_XT_ - NB_GT_) * 256 + tid;
        if (t >= CH_ * KTOT_) return;
        int j    = t & 7;
        int lane = (t >> 3) & 63;
        int kk   = t >> 9;             // 0..1151
        int kst  = kk % NKST_;
        int rg   = kk / NKST_;         // 0..15
        int row  = rg * 16 + (lane & 15);
        int kq   = kst * 32 + (lane >> 4) * 8 + j;   // k'
        int chunk = kq / KC_, r = kq % KC_;
        int tap = r / CPC_, ci = r % CPC_;
        int c = chunk * CPC_ + ci;
        wp2[t] = f2bf(w[(row * CH_ + c) * K2_ + tap]);
    }
}

// ---------------- standalone preps (fallback tiers only) ----------------
__global__ __launch_bounds__(256)
void prep_weight2(const float* __restrict__ w, ushort* __restrict__ wp2) {
    int t = blockIdx.x * 256 + threadIdx.x;
    if (t >= CH_ * KTOT_) return;
    int j    = t & 7;
    int lane = (t >> 3) & 63;
    int kk   = t >> 9;
    int kst  = kk % NKST_;
    int rg   = kk / NKST_;
    int row  = rg * 16 + (lane & 15);
    int kq   = kst * 32 + (lane >> 4) * 8 + j;
    int chunk = kq / KC_, r = kq % KC_;
    int tap = r / CPC_, ci = r % CPC_;
    int c = chunk * CPC_ + ci;
    wp2[t] = f2bf(w[(row * CH_ + c) * K2_ + tap]);
}

__global__ __launch_bounds__(256)
void prep_weight(const float* __restrict__ w, ushort* __restrict__ wp) {
    int t = blockIdx.x * 256 + threadIdx.x;
    if (t >= CH_ * KTOT_) return;
    int o  = t / KTOT_, kk = t % KTOT_;
    int chunk = kk / KC_, r = kk % KC_;
    int tap = r / CPC_, ci = r % CPC_;
    int c = chunk * CPC_ + ci;
    wp[t] = f2bf(w[(o * CH_ + c) * K2_ + tap]);
}

__global__ __launch_bounds__(256)
void prep_xt(const float* __restrict__ x, ushort* __restrict__ xt) {
    int bid = blockIdx.x;
    int hwT = bid % (HW_ / 128);
    int rest = bid / (HW_ / 128);
    int cT = rest & 3;
    int b  = rest >> 2;
    int hw0 = hwT * 128, c0 = cT * 64;
    int tid = threadIdx.x;
    int u = tid & 7, s = tid >> 3;
    const float* xb = x + ((long)b * CH_ + c0 + u * 8) * HW_ + hw0 + s * 4;
    float4 L[8];
    #pragma unroll
    for (int i = 0; i < 8; ++i) L[i] = *(const float4*)(xb + (long)i * HW_);
    ushort* xo = xt + ((long)b * HW_ + hw0 + s * 4) * CH_ + c0 + u * 8;
    #pragma unroll
    for (int j = 0; j < 4; ++j) {
        bf16x8 o;
        #pragma unroll
        for (int i = 0; i < 8; ++i) {
            float f = (j == 0) ? L[i].x : (j == 1) ? L[i].y : (j == 2) ? L[i].z : L[i].w;
            o[i] = (short)f2bf(f);
        }
        *(bf16x8*)(xo + (long)j * CH_) = o;
    }
}

__global__ __launch_bounds__(256)
void gating_kernel(const float* __restrict__ prob,
                   const float* __restrict__ table,
                   float* __restrict__ m_out,
                   float* __restrict__ off_out) {
    int pix = blockIdx.x * 256 + threadIdx.x;
    if (pix >= NPIX_) return;
    int b  = pix / HW_;
    int hw = pix % HW_;
    const float* pr = prob + (long)b * A_ * HW_ + hw;

    float v0 = -1e30f, v1 = -1e30f, v2 = -1e30f;
    int   i0 = 0, i1 = 0, i2 = 0;
    #pragma unroll 4
    for (int a = 0; a < A_; ++a) {
        float v = pr[(long)a * HW_];
        if (v > v0)      { v2=v1; i2=i1; v1=v0; i1=i0; v0=v; i0=a; }
        else if (v > v1) { v2=v1; i2=i1; v1=v;  i1=a; }
        else if (v > v2) { v2=v;  i2=a; }
    }
    float e1 = expf(v1 - v0), e2 = expf(v2 - v0);
    float inv = 1.0f / (1.0f + e1 + e2);
    float s0 = inv, s1 = e1*inv, s2 = e2*inv;
    float hard = (v0 > 0.5f) ? 1.0f : 0.0f;

    m_out[pix] = v0;
    const float* t0 = table + ((long)i0 * 18) * HW_ + hw;
    const float* t1 = table + ((long)i1 * 18) * HW_ + hw;
    const float* t2 = table + ((long)i2 * 18) * HW_ + hw;
    float* op = off_out + (long)pix * 18;
    #pragma unroll
    for (int c = 0; c < 18; ++c) {
        float o = s0 * t0[(long)c * HW_] + s1 * t1[(long)c * HW_] + s2 * t2[(long)c * HW_];
        op[c] = o * hard;
    }
}

// ======== im2col_k4 (proven 54us, round-6 verbatim): coalesced both ends ====
__global__ __launch_bounds__(576)
void im2col_k4(const ushort* __restrict__ xt,
               const float* __restrict__ m_arr,
               const float* __restrict__ off_arr,
               ushort* __restrict__ colg) {
    __shared__ __align__(16) ushort tb[36 * TSTR_];   // 37440 B

    const int tid  = threadIdx.x;
    const int lane = tid & 63;
    const int wv   = tid >> 6;            // 0..8
    const int bid  = (int)blockIdx.x;
    const int chI  = bid & 7;             // chunk == XCD slot
    const int pbk  = bid >> 3;            // 0..479 pixel-block
    const int pb   = pbk * PT2_;
    const int b    = pb / HW_;
    const int hw0  = pb % HW_;
    const ushort* xtb = xt + (long)b * HW_ * CH_;
    ushort* cgo = colg + (long)pbk * (NCHK_ * COLW_) + (long)chI * COLW_;

    const int sseg = lane & 3;
    const int qd   = lane >> 2;
    const int cb0  = chI * CPC_ + sseg * 8;

    int   coff[4][4];
    float cwgt[4][4];
    int   ldst[4];
    #pragma unroll
    for (int g = 0; g < 4; ++g) {
        int pr = g * 144 + wv * 16 + qd;   // bijective over 0..575
        int px = pr & 63, kt = pr >> 6;
        int hw = hw0 + px;
        int pix = pb + px;
        int h  = hw / W_, w_ = hw % W_;
        float m    = m_arr[pix];
        float2 ohw = *(const float2*)(off_arr + (long)pix * 18 + 2 * kt);
        float py  = (float)(h  + (kt / 3 - 1)) + ohw.x;
        float pxf = (float)(w_ + (kt % 3 - 1)) + ohw.y;
        float y0f = floorf(py), x0f = floorf(pxf);
        float dy = py - y0f,   dx = pxf - x0f;
        int y0 = (int)y0f, x0i = (int)x0f;
        int y1 = y0 + 1,   x1  = x0i + 1;
        float vy0 = (y0  >= 0 && y0  < H_) ? 1.f : 0.f;
        float vy1 = (y1  >= 0 && y1  < H_) ? 1.f : 0.f;
        float vx0 = (x0i >= 0 && x0i < W_) ? 1.f : 0.f;
        float vx1 = (x1  >= 0 && x1  < W_) ? 1.f : 0.f;
        int cy0 = min(max(y0, 0),  H_-1), cy1 = min(max(y1, 0), H_-1);
        int cx0 = min(max(x0i, 0), W_-1), cx1 = min(max(x1, 0), W_-1);
        coff[g][0] = (cy0*W_ + cx0) * CH_ + cb0;  cwgt[g][0] = (1.f-dy)*(1.f-dx)*vy0*vx0*m;
        coff[g][1] = (cy0*W_ + cx1) * CH_ + cb0;  cwgt[g][1] = (1.f-dy)*dx      *vy0*vx1*m;
        coff[g][2] = (cy1*W_ + cx0) * CH_ + cb0;  cwgt[g][2] = dy      *(1.f-dx)*vy1*vx0*m;
        coff[g][3] = (cy1*W_ + cx1) * CH_ + cb0;  cwgt[g][3] = dy      *dx      *vy1*vx1*m;
        ldst[g] = (kt * 4 + sseg) * TSTR_ + px * 8;   // transpose-buffer slot
    }

    // phase 1: 16 coalesced gathers -> blend -> 4 LDS writes
    bf16x8 d[4][4];
    #pragma unroll
    for (int g = 0; g < 4; ++g)
        #pragma unroll
        for (int c = 0; c < 4; ++c)
            d[g][c] = *(const bf16x8*)(xtb + coff[g][c]);
    #pragma unroll
    for (int g = 0; g < 4; ++g) {
        float a8[8];
        #pragma unroll
        for (int j = 0; j < 8; ++j) a8[j] = 0.f;
        #pragma unroll
        for (int c = 0; c < 4; ++c) {
            float wgt = cwgt[g][c];
            #pragma unroll
            for (int j = 0; j < 8; ++j)
                a8[j] = fmaf(wgt, bf2f((ushort)d[g][c][j]), a8[j]);
        }
        bf16x8 o;
        #pragma unroll
        for (int j = 0; j < 8; ++j) o[j] = (short)f2bf(a8[j]);
        *(bf16x8*)(&tb[ldst[g]]) = o;
    }
    __syncthreads();

    // phase 2: granule-major re-read (linear b128) -> 1KB-contiguous stores
    #pragma unroll
    for (int g = 0; g < 4; ++g) {
        const int G = g * 9 + wv;          // 0..35
        bf16x8 o = *(const bf16x8*)(&tb[G * TSTR_ + lane * 8]);
        *(bf16x8*)(cgo + (G * 64 + lane) * 8) = o;
    }
}

// ======== conv_gemm5 (round-6 verbatim, proven <53.3us) ========
__global__ __launch_bounds__(576, 1)
void conv_gemm5(const float* __restrict__ x,
                const ushort* __restrict__ colg,
                const ushort* __restrict__ wp2,
                const float* __restrict__ bias,
                float* __restrict__ out) {
    __shared__ __align__(16) ushort colL[4 * COLW_];   // 147456 B

    const int tid  = threadIdx.x;
    const int lane = tid & 63;
    const int wv   = tid >> 6;            // 0..8
    const int l15  = lane & 15;
    const int l16  = lane >> 4;
    const int bid  = (int)blockIdx.x;     // 0..239
    const int pb   = bid * PT5_;
    const int b    = pb / HW_;
    const int hw0  = pb % HW_;
    const long xb  = (long)b * CH_ * HW_;
    const long pbk64 = (long)bid * 2;     // two 64px col blocks

    f32x4 acc[2][8];
    #pragma unroll
    for (int m = 0; m < 2; ++m)
        #pragma unroll
        for (int n = 0; n < 8; ++n)
            acc[m][n] = (f32x4)(0.f);

    const int rg0 = wv * 2;
    const int mg  = wv * 32;

    auto STAGE = [&](int chI, int bufi) {
        #pragma unroll
        for (int hf = 0; hf < 2; ++hf) {
            const ushort* src = colg + ((pbk64 + hf) * NCHK_ + chI) * COLW_;
            ushort* dst = colL + (bufi * 2 + hf) * COLW_;
            #pragma unroll
            for (int i = 0; i < 4; ++i) {
                const int go = (wv * 4 + i) * 512;
                gld_lds16(src + go + lane * 8, dst + go);
            }
        }
    };
    auto COMPUTE = [&](int bufi, int chI) {
        if (wv < 8) {
            const ushort* wbase = wp2 + (((long)rg0 * NKST_ + chI * K2_) << 9) + (lane << 3);
            const long rstep = (long)NKST_ << 9;
            bf16x8 a0 = *(const bf16x8*)(wbase);
            bf16x8 a1 = *(const bf16x8*)(wbase + rstep);
            #pragma unroll
            for (int ks = 0; ks < K2_; ++ks) {
                bf16x8 a0n, a1n;
                if (ks < K2_ - 1) {                     // prefetch next ks
                    a0n = *(const bf16x8*)(wbase + ((ks + 1) << 9));
                    a1n = *(const bf16x8*)(wbase + rstep + ((ks + 1) << 9));
                }
                const ushort* cb0 = &colL[(bufi * 2) * COLW_ + ((ks * 4 + l16) * 64 + l15) * 8];
                const ushort* cb1 = cb0 + COLW_;
                bf16x8 b0 = *(const bf16x8*)(cb0);
                bf16x8 b1 = *(const bf16x8*)(cb0 + 128);
                bf16x8 b2 = *(const bf16x8*)(cb0 + 256);
                bf16x8 b3 = *(const bf16x8*)(cb0 + 384);
                bf16x8 b4 = *(const bf16x8*)(cb1);
                bf16x8 b5 = *(const bf16x8*)(cb1 + 128);
                bf16x8 b6 = *(const bf16x8*)(cb1 + 256);
                bf16x8 b7 = *(const bf16x8*)(cb1 + 384);
                __builtin_amdgcn_s_setprio(1);
                acc[0][0] = __builtin_amdgcn_mfma_f32_16x16x32_bf16(a0, b0, acc[0][0], 0, 0, 0);
                acc[0][1] = __builtin_amdgcn_mfma_f32_16x16x32_bf16(a0, b1, acc[0][1], 0, 0, 0);
                acc[0][2] = __builtin_amdgcn_mfma_f32_16x16x32_bf16(a0, b2, acc[0][2], 0, 0, 0);
                acc[0][3] = __builtin_amdgcn_mfma_f32_16x16x32_bf16(a0, b3, acc[0][3], 0, 0, 0);
                acc[0][4] = __builtin_amdgcn_mfma_f32_16x16x32_bf16(a0, b4, acc[0][4], 0, 0, 0);
                acc[0][5] = __builtin_amdgcn_mfma_f32_16x16x32_bf16(a0, b5, acc[0][5], 0, 0, 0);
                acc[0][6] = __builtin_amdgcn_mfma_f32_16x16x32_bf16(a0, b6, acc[0][6], 0, 0, 0);
                acc[0][7] = __builtin_amdgcn_mfma_f32_16x16x32_bf16(a0, b7, acc[0][7], 0, 0, 0);
                acc[1][0] = __builtin_amdgcn_mfma_f32_16x16x32_bf16(a1, b0, acc[1][0], 0, 0, 0);
                acc[1][1] = __builtin_amdgcn_mfma_f32_16x16x32_bf16(a1, b1, acc[1][1], 0, 0, 0);
                acc[1][2] = __builtin_amdgcn_mfma_f32_16x16x32_bf16(a1, b2, acc[1][2], 0, 0, 0);
                acc[1][3] = __builtin_amdgcn_mfma_f32_16x16x32_bf16(a1, b3, acc[1][3], 0, 0, 0);
                acc[1][4] = __builtin_amdgcn_mfma_f32_16x16x32_bf16(a1, b4, acc[1][4], 0, 0, 0);
                acc[1][5] = __builtin_amdgcn_mfma_f32_16x16x32_bf16(a1, b5, acc[1][5], 0, 0, 0);
                acc[1][6] = __builtin_amdgcn_mfma_f32_16x16x32_bf16(a1, b6, acc[1][6], 0, 0, 0);
                acc[1][7] = __builtin_amdgcn_mfma_f32_16x16x32_bf16(a1, b7, acc[1][7], 0, 0, 0);
                __builtin_amdgcn_s_setprio(0);
                if (ks < K2_ - 1) { a0 = a0n; a1 = a1n; }
            }
        }
    };

    STAGE(0, 0);
    __syncthreads();                       // buf0 ready
    for (int chI = 0; chI < NCHK_; ++chI) {
        const int cur = chI & 1, nxt = cur ^ 1;
        if (chI < NCHK_ - 1) STAGE(chI + 1, nxt);   // covered by ~1400cy compute
        COMPUTE(cur, chI);
        __syncthreads();
    }

    if (wv < 8) {
        #pragma unroll
        for (int m = 0; m < 2; ++m)
            #pragma unroll
            for (int n = 0; n < 8; ++n)
                #pragma unroll
                for (int r = 0; r < 4; ++r) {
                    int o  = mg + m * 16 + l16 * 4 + r;
                    int hw = hw0 + n * 16 + l15;
                    long oi = xb + (long)o * HW_ + hw;
                    out[oi] = acc[m][n][r] + bias[o] + x[oi];
                }
    }
}

// ======== v11 (proven 140 us) — mid-tier if ws can't hold col ========
__global__ __launch_bounds__(576)
void conv_mfma11(const float* __restrict__ x,
                 const ushort* __restrict__ xt,
                 const ushort* __restrict__ wp2,
                 const float* __restrict__ prob,
                 const float* __restrict__ table,
                 const float* __restrict__ bias,
                 float* __restrict__ out) {
    __shared__ __align__(16) ushort col[2][PT2_ * LSTR_];   // 75776 B
    __shared__ float off_l[PT2_ * 18];
    __shared__ float m_l[PT2_];

    const int tid  = threadIdx.x;
    const int lane = tid & 63;
    const int wv   = tid >> 6;
    const int l15  = lane & 15;
    const int l16  = lane >> 4;
    const int bid  = (int)blockIdx.x;
    const int bswz = (bid & 7) * (NBLK_ / 8) + (bid >> 3);
    const int pb   = bswz * PT2_;
    const int b    = pb / HW_;
    const int hw0  = pb % HW_;
    const long xb  = (long)b * CH_ * HW_;
    const ushort* xtb = xt + (long)b * HW_ * CH_;

    if (tid < PT2_) {
        const int px = tid;
        const int hw = hw0 + px;
        const float* pr = prob + (long)b * A_ * HW_ + hw;
        float v0 = -1e30f, v1 = -1e30f, v2 = -1e30f;
        int   i0 = 0, i1 = 0, i2 = 0;
        #pragma unroll 4
        for (int a = 0; a < A_; ++a) {
            float v = pr[(long)a * HW_];
            if (v > v0)      { v2=v1; i2=i1; v1=v0; i1=i0; v0=v; i0=a; }
            else if (v > v1) { v2=v1; i2=i1; v1=v;  i1=a; }
            else if (v > v2) { v2=v;  i2=a; }
        }
        float e1 = expf(v1 - v0), e2 = expf(v2 - v0);
        float inv = 1.0f / (1.0f + e1 + e2);
        float s0 = inv, s1 = e1*inv, s2 = e2*inv;
        float hard = (v0 > 0.5f) ? 1.0f : 0.0f;
        m_l[px] = v0;
        const float* t0 = table + ((long)i0 * 18) * HW_ + hw;
        const float* t1 = table + ((long)i1 * 18) * HW_ + hw;
        const float* t2 = table + ((long)i2 * 18) * HW_ + hw;
        #pragma unroll
        for (int c = 0; c < 18; ++c) {
            float o = s0 * t0[(long)c * HW_] + s1 * t1[(long)c * HW_] + s2 * t2[(long)c * HW_];
            off_l[px * 18 + c] = o * hard;
        }
    }
    __syncthreads();

    const int sseg = lane & 3;
    const int qd   = lane >> 2;
    int   coff[4][4];
    float cwgt[4][4];
    int   dsto[4];
    #pragma unroll
    for (int g = 0; g < 4; ++g) {
        int pr = g * 144 + wv * 16 + qd;
        int px = pr & 63, kt = pr >> 6;
        int hw = hw0 + px;
        int h  = hw / W_, w_ = hw % W_;
        float m    = m_l[px];
        float offh = off_l[px * 18 + 2*kt];
        float offw = off_l[px * 18 + 2*kt + 1];
        float py  = (float)(h  + (kt / 3 - 1)) + offh;
        float pxf = (float)(w_ + (kt % 3 - 1)) + offw;
        float y0f = floorf(py), x0f = floorf(pxf);
        float dy = py - y0f,   dx = pxf - x0f;
        int y0 = (int)y0f, x0i = (int)x0f;
        int y1 = y0 + 1,   x1  = x0i + 1;
        float vy0 = (y0  >= 0 && y0  < H_) ? 1.f : 0.f;
        float vy1 = (y1  >= 0 && y1  < H_) ? 1.f : 0.f;
        float vx0 = (x0i >= 0 && x0i < W_) ? 1.f : 0.f;
        float vx1 = (x1  >= 0 && x1  < W_) ? 1.f : 0.f;
        int cy0 = min(max(y0, 0),  H_-1), cy1 = min(max(y1, 0), H_-1);
        int cx0 = min(max(x0i, 0), W_-1), cx1 = min(max(x1, 0), W_-1);
        coff[g][0] = (cy0*W_ + cx0) * CH_;  cwgt[g][0] = (1.f-dy)*(1.f-dx)*vy0*vx0*m;
        coff[g][1] = (cy0*W_ + cx1) * CH_;  cwgt[g][1] = (1.f-dy)*dx      *vy0*vx1*m;
        coff[g][2] = (cy1*W_ + cx0) * CH_;  cwgt[g][2] = dy      *(1.f-dx)*vy1*vx0*m;
        coff[g][3] = (cy1*W_ + cx1) * CH_;  cwgt[g][3] = dy      *dx      *vy1*vx1*m;
        dsto[g] = px * LSTR_ + kt * CPC_ + sseg * 8;
    }

    f32x4 acc[2][4];
    #pragma unroll
    for (int m = 0; m < 2; ++m)
        #pragma unroll
        for (int n = 0; n < 4; ++n)
            acc[m][n] = (f32x4)(0.f);

    const int rg0 = wv * 2;
    const int mg  = wv * 32;

    bf16x8 d[2][4];

    auto LOADpair = [&](int chI, int g0) {
        const int cb0 = chI * CPC_ + sseg * 8;
        #pragma unroll
        for (int gg = 0; gg < 2; ++gg)
            #pragma unroll
            for (int c = 0; c < 4; ++c)
                d[gg][c] = *(const bf16x8*)(xtb + coff[g0 + gg][c] + cb0);
    };
    auto WRITEpair = [&](int bufi, int g0) {
        #pragma unroll
        for (int gg = 0; gg < 2; ++gg) {
            float a8[8];
            #pragma unroll
            for (int j = 0; j < 8; ++j) a8[j] = 0.f;
            #pragma unroll
            for (int c = 0; c < 4; ++c) {
                float wgt = cwgt[g0 + gg][c];
                #pragma unroll
                for (int j = 0; j < 8; ++j)
                    a8[j] = fmaf(wgt, bf2f((ushort)d[gg][c][j]), a8[j]);
            }
            bf16x8 o;
            #pragma unroll
            for (int j = 0; j < 8; ++j) o[j] = (short)f2bf(a8[j]);
            *(bf16x8*)(&col[bufi][dsto[g0 + gg]]) = o;
        }
    };
    auto COMPUTEhalf = [&](int bufi, int chI, int ks0, int ks1) {
        if (wv < 8) {
            for (int ks = ks0; ks < ks1; ++ks) {
                const int kst = chI * K2_ + ks;
                const ushort* wr = wp2 + (((long)rg0 * NKST_ + kst) << 9) + (lane << 3);
                bf16x8 a0 = *(const bf16x8*)(wr);
                bf16x8 a1 = *(const bf16x8*)(wr + (1l * NKST_ << 9));
                const ushort* cb = &col[bufi][l15 * LSTR_ + ks * 32 + 8 * l16];
                bf16x8 b0 = *(const bf16x8*)(cb);
                bf16x8 b1 = *(const bf16x8*)(cb + 16 * LSTR_);
                bf16x8 b2 = *(const bf16x8*)(cb + 32 * LSTR_);
                bf16x8 b3 = *(const bf16x8*)(cb + 48 * LSTR_);
                __builtin_amdgcn_s_setprio(1);
                acc[0][0] = __builtin_amdgcn_mfma_f32_16x16x32_bf16(a0, b0, acc[0][0], 0, 0, 0);
                acc[0][1] = __builtin_amdgcn_mfma_f32_16x16x32_bf16(a0, b1, acc[0][1], 0, 0, 0);
                acc[0][2] = __builtin_amdgcn_mfma_f32_16x16x32_bf16(a0, b2, acc[0][2], 0, 0, 0);
                acc[0][3] = __builtin_amdgcn_mfma_f32_16x16x32_bf16(a0, b3, acc[0][3], 0, 0, 0);
                acc[1][0] = __builtin_amdgcn_mfma_f32_16x16x32_bf16(a1, b0, acc[1][0], 0, 0, 0);
                acc[1][1] = __builtin_amdgcn_mfma_f32_16x16x32_bf16(a1, b1, acc[1][1], 0, 0, 0);
                acc[1][2] = __builtin_amdgcn_mfma_f32_16x16x32_bf16(a1, b2, acc[1][2], 0, 0, 0);
                acc[1][3] = __builtin_amdgcn_mfma_f32_16x16x32_bf16(a1, b3, acc[1][3], 0, 0, 0);
                __builtin_amdgcn_s_setprio(0);
            }
        }
    };

    LOADpair(0, 0); WRITEpair(0, 0);
    LOADpair(0, 2); WRITEpair(0, 2);
    __syncthreads();

    for (int chI = 0; chI < NCHK_; ++chI) {
        const int cur = chI & 1, nxt = cur ^ 1;
        const bool pf = (chI < NCHK_ - 1);
        if (pf) LOADpair(chI + 1, 0);
        COMPUTEhalf(cur, chI, 0, 4);
        if (pf) { WRITEpair(nxt, 0); LOADpair(chI + 1, 2); }
        COMPUTEhalf(cur, chI, 4, 9);
        if (pf) WRITEpair(nxt, 2);
        __syncthreads();
    }

    if (wv < 8) {
        #pragma unroll
        for (int m = 0; m < 2; ++m)
            #pragma unroll
            for (int n = 0; n < 4; ++n)
                #pragma unroll
                for (int r = 0; r < 4; ++r) {
                    int o  = mg + m * 16 + l16 * 4 + r;
                    int hw = hw0 + n * 16 + l15;
                    long oi = xb + (long)o * HW_ + hw;
                    out[oi] = acc[m][n][r] + bias[o] + x[oi];
                }
    }
}

// ======== v2 fallback (used if ws too small) ========
__global__ __launch_bounds__(576)
void conv_mfma2(const float* __restrict__ x,
                const ushort* __restrict__ wp,
                const float* __restrict__ bias,
                const float* __restrict__ m_arr,
                const float* __restrict__ off_arr,
                float* __restrict__ out) {
    __shared__ __align__(16) ushort col[PT2_ * LSTR_];

    const int tid  = threadIdx.x;
    const int lane = tid & 63;
    const int wv   = tid >> 6;
    const int l15  = lane & 15;
    const int l16  = lane >> 4;
    const int pb   = blockIdx.x * PT2_;
    const int b    = pb / HW_;
    const int hw0  = pb % HW_;
    const long xb  = (long)b * CH_ * HW_;

    int   id0, id1, id2, id3;
    float wg0, wg1, wg2, wg3;
    {
        int px = lane, kt = wv;
        int hw = hw0 + px;
        int h  = hw / W_, w_ = hw % W_;
        int pix = b * HW_ + hw;
        float m    = m_arr[pix];
        float offh = off_arr[(long)pix * 18 + 2*kt];
        float offw = off_arr[(long)pix * 18 + 2*kt + 1];
        float py = (float)(h  + (kt / 3 - 1)) + offh;
        float px_= (float)(w_ + (kt % 3 - 1)) + offw;
        float y0f = floorf(py), x0f = floorf(px_);
        float dy = py - y0f,   dx = px_ - x0f;
        int y0 = (int)y0f, x0 = (int)x0f;
        int y1 = y0 + 1,   x1 = x0 + 1;
        float vy0 = (y0 >= 0 && y0 < H_) ? 1.f : 0.f;
        float vy1 = (y1 >= 0 && y1 < H_) ? 1.f : 0.f;
        float vx0 = (x0 >= 0 && x0 < W_) ? 1.f : 0.f;
        float vx1 = (x1 >= 0 && x1 < W_) ? 1.f : 0.f;
        int cy0 = min(max(y0, 0), H_-1), cy1 = min(max(y1, 0), H_-1);
        int cx0 = min(max(x0, 0), W_-1), cx1 = min(max(x1, 0), W_-1);
        id0 = cy0*W_ + cx0;  wg0 = (1.f-dy)*(1.f-dx)*vy0*vx0*m;
        id1 = cy0*W_ + cx1;  wg1 = (1.f-dy)*dx      *vy0*vx1*m;
        id2 = cy1*W_ + cx0;  wg2 = dy      *(1.f-dx)*vy1*vx0*m;
        id3 = cy1*W_ + cx1;  wg3 = dy      *dx      *vy1*vx1*m;
    }

    f32x4 acc[4][2];
    #pragma unroll
    for (int m = 0; m < 4; ++m)
        #pragma unroll
        for (int n = 0; n < 2; ++n)
            acc[m][n] = (f32x4)(0.f);

    const int mg = (wv & 3) * 64;
    const int pg = (wv >> 2) * 32;

    for (int chI = 0; chI < NCHK_; ++chI) {
        __syncthreads();
        {
            const int c0 = chI * CPC_;
            ushort* dst = &col[lane * LSTR_ + wv * CPC_];
            #pragma unroll
            for (int c8 = 0; c8 < 4; ++c8) {
                bf16x8 pk;
                #pragma unroll
                for (int j = 0; j < 8; ++j) {
                    const float* xs = x + xb + (long)(c0 + c8*8 + j) * HW_;
                    float v = wg0 * xs[id0] + wg1 * xs[id1]
                            + wg2 * xs[id2] + wg3 * xs[id3];
                    pk[j] = (short)f2bf(v);
                }
                *(bf16x8*)(dst + c8 * 8) = pk;
            }
        }
        __syncthreads();
        if (wv < 8) {
            #pragma unroll
            for (int ks = 0; ks < K2_; ++ks) {
                const int kg = chI * KC_ + ks * 32 + 8 * l16;
                const ushort* wr = wp + (long)(mg + l15) * KTOT_ + kg;
                bf16x8 a0 = *(const bf16x8*)(wr);
                bf16x8 a1 = *(const bf16x8*)(wr + 16 * KTOT_);
                bf16x8 a2 = *(const bf16x8*)(wr + 32 * KTOT_);
                bf16x8 a3 = *(const bf16x8*)(wr + 48 * KTOT_);
                const ushort* cb = &col[(pg + l15) * LSTR_ + ks * 32 + 8 * l16];
                bf16x8 b0 = *(const bf16x8*)(cb);
                bf16x8 b1 = *(const bf16x8*)(cb + 16 * LSTR_);
                acc[0][0] = __builtin_amdgcn_mfma_f32_16x16x32_bf16(a0, b0, acc[0][0], 0, 0, 0);
                acc[0][1] = __builtin_amdgcn_mfma_f32_16x16x32_bf16(a0, b1, acc[0][1], 0, 0, 0);
                acc[1][0] = __builtin_amdgcn_mfma_f32_16x16x32_bf16(a1, b0, acc[1][0], 0, 0, 0);
                acc[1][1] = __builtin_amdgcn_mfma_f32_16x16x32_bf16(a1, b1, acc[1][1], 0, 0, 0);
                acc[2][0] = __builtin_amdgcn_mfma_f32_16x16x32_bf16(a2, b0, acc[2][0], 0, 0, 0);
                acc[2][1] = __builtin_amdgcn_mfma_f32_16x16x32_bf16(a2, b1, acc[2][1], 0, 0, 0);
                acc[3][0] = __builtin_amdgcn_mfma_f32_16x16x32_bf16(a3, b0, acc[3][0], 0, 0, 0);
                acc[3][1] = __builtin_amdgcn_mfma_f32_16x16x32_bf16(a3, b1, acc[3][1], 0, 0, 0);
            }
        }
    }

    if (wv < 8) {
        #pragma unroll
        for (int m = 0; m < 4; ++m)
            #pragma unroll
            for (int n = 0; n < 2; ++n)
                #pragma unroll
                for (int r = 0; r < 4; ++r) {
                    int o  = mg + m * 16 + l16 * 4 + r;
                    int hw = hw0 + pg + n * 16 + l15;
                    long oi = xb + (long)o * HW_ + hw;
                    out[oi] = acc[m][n][r] + bias[o] + x[oi];
                }
    }
}

extern "C" void kernel_launch(void* const* d_in, const int* in_sizes, int n_in,
                              void* d_out, int out_size, void* d_ws, size_t ws_size,
                              hipStream_t stream) {
    const float* x      = (const float*)d_in[0];
    const float* prob   = (const float*)d_in[1];
    const float* table  = (const float*)d_in[2];
    const float* weight = (const float*)d_in[3];
    const float* bias   = (const float*)d_in[4];
    float* out = (float*)d_out;

    const size_t wp_bytes  = (size_t)CH_ * KTOT_ * 2;          // 1,179,648
    const size_t m_bytes   = (size_t)NPIX_ * 4;                // 122,880
    const size_t off_bytes = (size_t)NPIX_ * 18 * 4;           // 2,211,840
    const size_t xt_bytes  = (size_t)NPIX_ * CH_ * 2;          // 15,728,640
    const size_t col_bytes = (size_t)NBLK_ * NCHK_ * COLB_;    // 141,557,760

    ushort* wp_ws  = (ushort*)d_ws;
    float*  m_ws   = (float*)((char*)d_ws + wp_bytes);
    float*  off_ws = (float*)((char*)d_ws + wp_bytes + m_bytes);
    ushort* xt_ws  = (ushort*)((char*)d_ws + wp_bytes + m_bytes + off_bytes);
    ushort* col_ws = (ushort*)((char*)d_ws + wp_bytes + m_bytes + off_bytes + xt_bytes);

    const size_t need_v11 = wp_bytes + m_bytes + off_bytes + xt_bytes;
    const size_t need_v21 = need_v11 + col_bytes;

    if (ws_size >= need_v21) {
        prep_all<<<NB_ALL_, 256, 0, stream>>>(x, xt_ws, prob, table, m_ws, off_ws,
                                              weight, wp_ws);
        im2col_k4<<<NBLK_ * NCHK_, 576, 0, stream>>>(xt_ws, m_ws, off_ws, col_ws);
        conv_gemm5<<<NB5_, 576, 0, stream>>>(x, col_ws, wp_ws, bias, out);
    } else if (ws_size >= need_v11) {
        prep_weight2<<<(CH_ * KTOT_ + 255) / 256, 256, 0, stream>>>(weight, wp_ws);
        prep_xt<<<(HW_ / 128) * 4 * B_, 256, 0, stream>>>(x, xt_ws);
        conv_mfma11<<<NBLK_, 576, 0, stream>>>(x, xt_ws, wp_ws, prob, table, bias, out);
    } else {
        gating_kernel<<<NPIX_ / 256, 256, 0, stream>>>(prob, table, m_ws, off_ws);
        prep_weight<<<(CH_ * KTOT_ + 255) / 256, 256, 0, stream>>>(weight, wp_ws);
        conv_mfma2<<<NPIX_ / PT2_, 576, 0, stream>>>(x, wp_ws, bias, m_ws, off_ws, out);
    }
}